// Round 11
// baseline (455.526 us; speedup 1.0000x reference)
//
#include <hip/hip_runtime.h>
#include <stdint.h>

typedef __attribute__((ext_vector_type(8))) _Float16 half8;
typedef __attribute__((ext_vector_type(8))) short short8;
typedef __attribute__((ext_vector_type(4))) float f32x4;

#define FMIN_F (-3.4028234663852886e38f)

__device__ __forceinline__ unsigned short rne_bf16(float x) {
  unsigned u = __float_as_uint(x);
  unsigned r = (u + 0x7FFFu + ((u >> 16) & 1u)) >> 16;
  return (unsigned short)r;
}

__device__ __forceinline__ void split16(float x, unsigned short& h, unsigned short& l) {
  _Float16 hh = (_Float16)x;
  float r = x - (float)hh;
  _Float16 ll = (_Float16)r;
  union { _Float16 f; unsigned short u; } a, b;
  a.f = hh; b.f = ll;
  h = a.u; l = b.u;
}

__device__ __forceinline__ void glds16(const unsigned short* g, unsigned short* l) {
  __builtin_amdgcn_global_load_lds(
      (const __attribute__((address_space(1))) unsigned int*)g,
      (__attribute__((address_space(3))) unsigned int*)l, 16, 0, 0);
}

// ---- tokens f32 -> A2=[Ah|Al] rows + per-block partial column sums (NO atomics)
// single pass over all 65536 rows: 4096 blocks x 16 rows; 512 blocks per batch
__global__ __launch_bounds__(256) void k_split(const float* __restrict__ tok,
    const int* __restrict__ lengths, unsigned short* __restrict__ A2,
    float* __restrict__ gpart) {
  __shared__ float ps[512];
  int wg = blockIdx.x, tid = threadIdx.x;
  int colv = tid & 127;
  int rh = tid >> 7;
  int r0 = wg << 4;                       // 16 rows per block
  int b0 = r0 >> 13;                      // batch
  int part = wg & 511;                    // block index within batch
  int len = lengths[b0];
  float sx = 0.f, sy = 0.f, sz = 0.f, sw = 0.f;
#pragma unroll
  for (int i = 0; i < 8; ++i) {
    int row = r0 + (i << 1) + rh;
    const float4 v = ((const float4*)(tok + (size_t)row * 512))[colv];
    ushort4 oh, ol;
    split16(v.x, oh.x, ol.x); split16(v.y, oh.y, ol.y);
    split16(v.z, oh.z, ol.z); split16(v.w, oh.w, ol.w);
    *(ushort4*)(A2 + (size_t)row * 1024 + colv * 4) = oh;
    *(ushort4*)(A2 + (size_t)row * 1024 + 512 + colv * 4) = ol;
    if ((row & 8191) < len) { sx += v.x; sy += v.y; sz += v.z; sw += v.w; }
  }
  if (rh == 0) {
    ps[colv * 4 + 0] = sx; ps[colv * 4 + 1] = sy;
    ps[colv * 4 + 2] = sz; ps[colv * 4 + 3] = sw;
  }
  __syncthreads();
  if (rh == 1) {
    ps[colv * 4 + 0] += sx; ps[colv * 4 + 1] += sy;
    ps[colv * 4 + 2] += sz; ps[colv * 4 + 3] += sw;
  }
  __syncthreads();
  float* gp = gpart + ((size_t)b0 * 512 + part) * 512;
  gp[tid] = ps[tid];
  gp[tid + 256] = ps[tid + 256];
}

// ---- reduce partials -> gsum[b][512]; grid (8,2), 256 cols per block ----------
__global__ __launch_bounds__(256) void k_gred(const float* __restrict__ gpart,
    float* __restrict__ gsum) {
  int b = blockIdx.x, half = blockIdx.y, tid = threadIdx.x;
  int c = half * 256 + tid;
  float a0 = 0.f;
  for (int part = 0; part < 512; ++part)
    a0 += gpart[((size_t)b * 512 + part) * 512 + c];
  gsum[b * 512 + c] = a0;
}

// ---- pack comp [Wv|Ww] transposed to W2 [1024][Wh(512)|Wl(512)] (coalesced) ---
__global__ __launch_bounds__(256) void k_wsplit(const float* __restrict__ wv,
    const float* __restrict__ ww, unsigned short* __restrict__ W2) {
  __shared__ float t[64][65];
  int kk0 = blockIdx.x * 64, d0 = blockIdx.y * 64, m = blockIdx.z;
  const float* W = m ? ww : wv;
  int tid = threadIdx.x;
  for (int i = tid; i < 4096; i += 256) {
    int k = i >> 6, d = i & 63;
    t[k][d] = W[(size_t)(kk0 + k) * 512 + d0 + d];
  }
  __syncthreads();
  int dr = tid >> 2, kq = tid & 3;
  int d = d0 + dr;
  int n = (d >> 5) * 64 + m * 32 + (d & 31);
  size_t baseH = (size_t)n * 1024 + kk0 + kq * 16;
  for (int q = 0; q < 16; ++q) {
    unsigned short hh, ll;
    split16(t[kq * 16 + q][dr], hh, ll);
    W2[baseH + q] = hh;
    W2[baseH + 512 + q] = ll;
  }
}

// ---- pack pool [Wk|Wv] transposed to PW2 [1024][512] bf16 ---------------------
__global__ __launch_bounds__(256) void k_wpool(const float* __restrict__ wk,
    const float* __restrict__ wv, unsigned short* __restrict__ PW) {
  __shared__ float t[64][65];
  int kk0 = blockIdx.x * 64, d0 = blockIdx.y * 64, m = blockIdx.z;
  const float* W = m ? wv : wk;
  int tid = threadIdx.x;
  for (int i = tid; i < 4096; i += 256) {
    int k = i >> 6, d = i & 63;
    t[k][d] = W[(size_t)(kk0 + k) * 512 + d0 + d];
  }
  __syncthreads();
  int dr = tid >> 2, kq = tid & 3;
  int n = m * 512 + d0 + dr;
  size_t base = (size_t)n * 512 + kk0 + kq * 16;
  for (int q = 0; q < 16; ++q)
    PW[base + q] = rne_bf16(t[kq * 16 + q][dr]);
}

// ---- 128x128-tile split-f16 GEMM + XOR-swizzled LDS (single dispatch) ---------
__global__ __launch_bounds__(256) void k_gemm128(
    const unsigned short* __restrict__ A2, const unsigned short* __restrict__ W2,
    const float* __restrict__ bv, const float* __restrict__ bw,
    const float* __restrict__ cpos, const int* __restrict__ lengths,
    float* __restrict__ ctx) {
  __shared__ __align__(16) unsigned short Ash[128 * 64];
  __shared__ __align__(16) unsigned short Asl[128 * 64];
  __shared__ __align__(16) unsigned short Bsh[128 * 64];
  __shared__ __align__(16) unsigned short Bsl[128 * 64];
  __shared__ float pos_s[32 * 64];
  int mt = blockIdx.x, ny = blockIdx.y;
  int tid = threadIdx.x;
  int wave = tid >> 6, lane = tid & 63;
  int m0 = mt << 7, n0 = ny << 7;
  for (int i = tid; i < 2048; i += 256) {
    int s = i >> 6, c = i & 63;
    pos_s[i] = cpos[s * 512 + ny * 64 + c];
  }
  f32x4 acc[4][4];
#pragma unroll
  for (int i = 0; i < 4; ++i)
#pragma unroll
    for (int j = 0; j < 4; ++j) acc[i][j] = (f32x4){0.f, 0.f, 0.f, 0.f};
  int lrow = lane >> 3, lcol = lane & 7;
  int wm = wave >> 1, wn = wave & 1;
  int l15 = lane & 15, lg4 = lane >> 4;
  int scs_ = (lcol ^ lrow) * 8;     // swizzled source chunk; LDS dest stays linear
  int rx = (l15 & 7);               // read-side row XOR key
  for (int kk = 0; kk < 8; ++kk) {
    int k0 = kk << 6;
#pragma unroll
    for (int j = 0; j < 4; ++j) {
      int r = wave * 32 + j * 8 + lrow;
      size_t ga = (size_t)(m0 + r) * 1024 + k0 + scs_;
      size_t gb = (size_t)(n0 + r) * 1024 + k0 + scs_;
      int ls = r * 64 + lcol * 8;
      glds16(A2 + ga, Ash + ls);
      glds16(A2 + ga + 512, Asl + ls);
      glds16(W2 + gb, Bsh + ls);
      glds16(W2 + gb + 512, Bsl + ls);
    }
    __syncthreads();
#pragma unroll
    for (int ks = 0; ks < 2; ++ks) {
      int cofs = ((ks * 4 + lg4) ^ rx) * 8;   // XOR-swizzled read offset
      half8 bh[4], bl[4];
#pragma unroll
      for (int i = 0; i < 4; ++i) {
        bh[i] = *(const half8*)(Bsh + (wn * 64 + i * 16 + l15) * 64 + cofs);
        bl[i] = *(const half8*)(Bsl + (wn * 64 + i * 16 + l15) * 64 + cofs);
      }
#pragma unroll
      for (int mi = 0; mi < 4; ++mi) {
        half8 ah = *(const half8*)(Ash + (wm * 64 + mi * 16 + l15) * 64 + cofs);
        half8 al = *(const half8*)(Asl + (wm * 64 + mi * 16 + l15) * 64 + cofs);
#pragma unroll
        for (int ni = 0; ni < 4; ++ni) {
          acc[mi][ni] = __builtin_amdgcn_mfma_f32_16x16x32_f16(ah, bh[ni], acc[mi][ni], 0, 0, 0);
          acc[mi][ni] = __builtin_amdgcn_mfma_f32_16x16x32_f16(al, bh[ni], acc[mi][ni], 0, 0, 0);
          acc[mi][ni] = __builtin_amdgcn_mfma_f32_16x16x32_f16(ah, bl[ni], acc[mi][ni], 0, 0, 0);
        }
      }
    }
    __syncthreads();
  }
  // epilogue: per (32-token block, d): softmax over s of logits, weighted value sum
  int bidx = m0 >> 13;
  int len = lengths[bidx];
#pragma unroll
  for (int niv = 0; niv < 2; ++niv) {
    int d = (ny * 2 + wn) * 32 + niv * 16 + l15;   // global d in [0,512)
    int dloc = wn * 32 + niv * 16 + l15;           // wg-local d in [0,64)
    float bwv = bw[d], bvv = bv[d];
#pragma unroll
    for (int blk = 0; blk < 2; ++blk) {
      int growL = m0 + wm * 64 + blk * 32;
      int nb = (growL & 8191) >> 5;
      int vcnt = min(max(len - nb * 32, 0), 32);
      float lg[8], vl[8];
      float mx = FMIN_F;
#pragma unroll
      for (int j = 0; j < 8; ++j) {
        int mi = blk * 2 + (j >> 2);
        int r = j & 3;
        int s = ((j >> 2) << 4) + lg4 * 4 + r;
        float L = acc[mi][2 + niv][r] + bwv + pos_s[s * 64 + dloc];
        float V = acc[mi][niv][r] + bvv;
        lg[j] = L; vl[j] = V;
        if (s < vcnt) mx = fmaxf(mx, L);
      }
      mx = fmaxf(mx, __shfl_xor(mx, 16));
      mx = fmaxf(mx, __shfl_xor(mx, 32));
      float num = 0.f, den = 0.f;
#pragma unroll
      for (int j = 0; j < 8; ++j) {
        int s = ((j >> 2) << 4) + lg4 * 4 + (j & 3);
        if (s < vcnt) {
          float e = __expf(lg[j] - mx);
          num += e * vl[j];
          den += e;
        }
      }
      num += __shfl_xor(num, 16); num += __shfl_xor(num, 32);
      den += __shfl_xor(den, 16); den += __shfl_xor(den, 32);
      float o = (den > 0.f) ? (num / den) : 0.f;
      if (lg4 == 0)
        ctx[((size_t)bidx * 256 + nb) * 512 + d] = o;
    }
  }
}

// ---- fused: rmsnorm(ctx) -> bt  AND  keys = rmsnorm(bt @ idx_k_w + kb, kn) ----
__global__ __launch_bounds__(64) void k_btk(const float* __restrict__ ctx,
    const float* __restrict__ nw, const float* __restrict__ kw,
    const float* __restrict__ kb, const float* __restrict__ knw,
    float* __restrict__ bt, float* __restrict__ keys) {
  int row = blockIdx.x, lane = threadIdx.x;
  __shared__ float bs[512];
  const float* cp = ctx + (size_t)row * 512 + lane * 8;
  float x[8];
#pragma unroll
  for (int j = 0; j < 8; ++j) x[j] = cp[j];
  float ss = 0.f;
#pragma unroll
  for (int j = 0; j < 8; ++j) ss += x[j] * x[j];
#pragma unroll
  for (int o = 1; o < 64; o <<= 1) ss += __shfl_xor(ss, o);
  float sc = rsqrtf(ss * (1.f / 512.f) + 1e-6f);
  float* op = bt + (size_t)row * 512 + lane * 8;
  const float* nwp = nw + lane * 8;
#pragma unroll
  for (int j = 0; j < 8; ++j) {
    float y = x[j] * sc * nwp[j];
    op[j] = y;
    bs[lane * 8 + j] = y;
  }
  __syncthreads();
  float a = kb[lane];
  for (int k = 0; k < 512; ++k) a += bs[k] * kw[k * 64 + lane];
  float s2 = a * a;
#pragma unroll
  for (int o = 1; o < 64; o <<= 1) s2 += __shfl_xor(s2, o);
  keys[(size_t)row * 64 + lane] = a * rsqrtf(s2 * (1.f / 64.f) + 1e-6f) * knw[lane];
}

// ---- per-b: ql, qh, hw, scores, top-64 (keys staged in LDS, padded stride) ----
__global__ __launch_bounds__(256) void k_sel(
    const float* __restrict__ query, const float* __restrict__ keys,
    const int* __restrict__ lengths,
    const float* __restrict__ qdw, const float* __restrict__ qdb,
    const float* __restrict__ quw, const float* __restrict__ qub,
    const float* __restrict__ hww, const float* __restrict__ hwb,
    const float* __restrict__ qnw, int* __restrict__ idxs) {
  int b = blockIdx.x, tid = threadIdx.x;
  __shared__ float qs[512], qls[64], qhs[512], hws[8], scs[256];
  __shared__ float ks_s[256 * 65];        // padded: conflict-free
  int wave = tid >> 6, lane = tid & 63;
  {
    const float* kb_g = keys + (size_t)b * 256 * 64;
    for (int r = wave; r < 256; r += 4)
      ks_s[r * 65 + lane] = kb_g[r * 64 + lane];
  }
  for (int i = tid; i < 512; i += 256) qs[i] = query[b * 512 + i];
  __syncthreads();
  if (tid < 64) {
    float a = qdb[tid];
    for (int k = 0; k < 512; ++k) a += qs[k] * qdw[k * 64 + tid];
    float ss = a * a;
#pragma unroll
    for (int o = 1; o < 64; o <<= 1) ss += __shfl_xor(ss, o);
    qls[tid] = a * rsqrtf(ss * (1.f / 64.f) + 1e-6f) * qnw[tid];
  }
  __syncthreads();
  for (int j = tid; j < 512; j += 256) {
    float a = qub[j];
    for (int k = 0; k < 64; ++k) a += qls[k] * quw[k * 512 + j];
    qhs[j] = a;
  }
  if (tid < 8) {
    float a = hwb[tid];
    for (int k = 0; k < 512; ++k) a += qs[k] * hww[k * 8 + tid];
    hws[tid] = a;
  }
  __syncthreads();
  if (tid == 0) {
    float m = hws[0];
    for (int h = 1; h < 8; ++h) m = fmaxf(m, hws[h]);
    float s = 0.f, e[8];
    for (int h = 0; h < 8; ++h) { e[h] = __expf(hws[h] - m); s += e[h]; }
    for (int h = 0; h < 8; ++h) hws[h] = e[h] / s;
  }
  __syncthreads();
  {
    int len = lengths[b];
    int n = tid;
    float sc = FMIN_F;
    if (n * 32 < len) {
      sc = 0.f;
      const float* kr = ks_s + n * 65;
      for (int h = 0; h < 8; ++h) {
        float dp = 0.f;
#pragma unroll
        for (int i = 0; i < 64; ++i) dp += qhs[h * 64 + i] * kr[i];
        sc += fmaxf(dp, 0.f) * hws[h];
      }
    }
    scs[n] = sc;
  }
  __syncthreads();
  if (tid < 64) {
    unsigned long long kk[4];
#pragma unroll
    for (int j = 0; j < 4; ++j) {
      int n = j * 64 + tid;
      unsigned u = __float_as_uint(scs[n]);
      u = (u & 0x80000000u) ? ~u : (u | 0x80000000u);
      kk[j] = ((unsigned long long)u << 32) | (unsigned long long)(255 - n);
    }
    for (int r = 0; r < 64; ++r) {
      unsigned long long m = kk[0];
      if (kk[1] > m) m = kk[1];
      if (kk[2] > m) m = kk[2];
      if (kk[3] > m) m = kk[3];
#pragma unroll
      for (int o = 1; o < 64; o <<= 1) {
        unsigned long long t = __shfl_xor(m, o);
        if (t > m) m = t;
      }
      if (tid == 0) idxs[b * 64 + r] = 255 - (int)(m & 0xFFull);
#pragma unroll
      for (int j = 0; j < 4; ++j) if (kk[j] == m) kk[j] = 0ull;
    }
  }
}

// ---- assemble src rows (recent | sel | gtok) as bf16 + smask + zero pad rows --
__global__ __launch_bounds__(128) void k_src(const float* __restrict__ tok,
    const float* __restrict__ bt, const float* __restrict__ gsum,
    const int* __restrict__ lengths, const int* __restrict__ idxs,
    unsigned short* __restrict__ src_bf, int* __restrict__ smask) {
  int b = blockIdx.x, n = blockIdx.y, tid = threadIdx.x;
  int d0 = tid * 4;
  if (n >= 193) {   // zero a pad row (rows 1544..1663 of the 1664-row buffer)
    size_t prow = 1544 + (size_t)b * 15 + (n - 193);
    ushort4 z; z.x = 0; z.y = 0; z.z = 0; z.w = 0;
    *(ushort4*)(src_bf + prow * 512 + d0) = z;
    return;
  }
  int len = lengths[b];
  float v0 = 0.f, v1 = 0.f, v2 = 0.f, v3 = 0.f;
  int sm = 0;
  if (n < 128) {
    int cl = min(max(len, 0), 8192);
    int start = max(cl - 128, 0);
    int pos = min(start + n, 8191);
    bool vis = n < min(cl, 128);
    sm = vis ? 0 : 1;
    if (vis) {
      const float* tp = tok + ((size_t)b * 8192 + pos) * 512 + d0;
      float pn = (float)n;
#pragma unroll
      for (int j = 0; j < 4; ++j) {
        int d = d0 + j;
        int i = d >> 1;
        float ang = pn * __expf(-9.210340371976184f * ((float)i * (1.f / 256.f)));
        float pe = (d & 1) ? cosf(ang) : sinf(ang);
        float t = tp[j] + pe;
        if (j == 0) v0 = t; else if (j == 1) v1 = t; else if (j == 2) v2 = t; else v3 = t;
      }
    }
  } else if (n < 192) {
    int idx = idxs[b * 64 + (n - 128)];
    sm = (idx * 32 >= len) ? 1 : 0;
    const float* bp = bt + ((size_t)b * 256 + idx) * 512 + d0;
    v0 = bp[0]; v1 = bp[1]; v2 = bp[2]; v3 = bp[3];
  } else {
    sm = 0;
    float inv = 1.f / (float)max(len, 1);
    const float* gp = gsum + b * 512 + d0;
    v0 = gp[0] * inv; v1 = gp[1] * inv; v2 = gp[2] * inv; v3 = gp[3] * inv;
  }
  ushort4 o;
  o.x = rne_bf16(v0); o.y = rne_bf16(v1); o.z = rne_bf16(v2); o.w = rne_bf16(v3);
  *(ushort4*)(src_bf + ((size_t)b * 193 + n) * 512 + d0) = o;
  if (tid == 0) smask[b * 193 + n] = sm;
}

// ---- pooling k/v GEMM (bf16 MFMA): kv[r][0:512]=src@Wk, [512:1024]=src@Wv -----
__global__ __launch_bounds__(256) void k_kvm(
    const unsigned short* __restrict__ src_bf, const unsigned short* __restrict__ PW,
    float* __restrict__ kv) {
  __shared__ __align__(16) unsigned short As[128 * 64];
  __shared__ __align__(16) unsigned short Bs[128 * 64];
  int m0 = blockIdx.x << 7, n0 = blockIdx.y << 7;
  int tid = threadIdx.x;
  int wave = tid >> 6, lane = tid & 63;
  int wm = wave >> 1, wn = wave & 1;
  int l15 = lane & 15, lg4 = lane >> 4;
  int lrow = lane >> 3, lcol = lane & 7;
  f32x4 acc[4][4];
#pragma unroll
  for (int i = 0; i < 4; ++i)
#pragma unroll
    for (int j = 0; j < 4; ++j) acc[i][j] = (f32x4){0.f, 0.f, 0.f, 0.f};
  for (int kk = 0; kk < 8; ++kk) {
    int k0 = kk << 6;
#pragma unroll
    for (int j = 0; j < 4; ++j) {
      int r = wave * 32 + j * 8 + lrow;
      glds16(src_bf + (size_t)(m0 + r) * 512 + k0 + lcol * 8, As + r * 64 + lcol * 8);
      glds16(PW + (size_t)(n0 + r) * 512 + k0 + lcol * 8, Bs + r * 64 + lcol * 8);
    }
    __syncthreads();
#pragma unroll
    for (int ks = 0; ks < 2; ++ks) {
      int kb = ks * 32 + lg4 * 8;
      short8 av[4], bf[4];
#pragma unroll
      for (int i = 0; i < 4; ++i) {
        av[i] = *(const short8*)(As + (wm * 64 + i * 16 + l15) * 64 + kb);
        bf[i] = *(const short8*)(Bs + (wn * 64 + i * 16 + l15) * 64 + kb);
      }
#pragma unroll
      for (int mi = 0; mi < 4; ++mi)
#pragma unroll
        for (int ni = 0; ni < 4; ++ni)
          acc[mi][ni] = __builtin_amdgcn_mfma_f32_16x16x32_bf16(av[mi], bf[ni], acc[mi][ni], 0, 0, 0);
    }
    __syncthreads();
  }
#pragma unroll
  for (int mi = 0; mi < 4; ++mi)
#pragma unroll
    for (int ni = 0; ni < 4; ++ni)
#pragma unroll
      for (int rr = 0; rr < 4; ++rr) {
        int grow = m0 + wm * 64 + mi * 16 + lg4 * 4 + rr;
        kv[(size_t)grow * 1024 + n0 + wn * 64 + ni * 16 + l15] = acc[mi][ni][rr];
      }
}

// ---- qproj = query @ pool_q_w + pool_q_b (direct, no atomics/memset) ----------
__global__ __launch_bounds__(256) void k_qproj(const float* __restrict__ query,
    const float* __restrict__ pqw, const float* __restrict__ pqb,
    float* __restrict__ qp) {
  int b = blockIdx.x;
  int c = blockIdx.y * 256 + threadIdx.x;
  __shared__ float qs[512];
  for (int i = threadIdx.x; i < 512; i += 256) qs[i] = query[b * 512 + i];
  __syncthreads();
  float a = pqb[c];
  for (int k = 0; k < 512; ++k) a += qs[k] * pqw[(size_t)k * 512 + c];
  qp[b * 512 + c] = a;
}

// ---- latent cross-attention + rmsnorm -> out (coalesced, branchless PV) -------
__global__ __launch_bounds__(256) void k_attn(const float* __restrict__ kv,
    const float* __restrict__ qproj, const float* __restrict__ latents,
    const float* __restrict__ pkb, const float* __restrict__ pvb,
    const float* __restrict__ pnw, const int* __restrict__ smask,
    float* __restrict__ out) {
  int b = blockIdx.x, l = blockIdx.y, tid = threadIdx.x;
  int wave = tid >> 6, lane = tid & 63;
  __shared__ float lq_s[512];
  __shared__ float w_s[256];
  __shared__ float red_s[256];
  __shared__ int sm_s[256];
  for (int i = tid; i < 512; i += 256) lq_s[i] = latents[l * 512 + i] + qproj[b * 512 + i];
  sm_s[tid] = (tid < 193) ? smask[b * 193 + tid] : 1;
  w_s[tid] = FMIN_F;
  __syncthreads();
  red_s[tid] = (tid < 193 && sm_s[tid]) ? 1.f : 0.f;
  __syncthreads();
  for (int s = 128; s > 0; s >>= 1) { if (tid < s) red_s[tid] += red_s[tid + s]; __syncthreads(); }
  bool allm = (red_s[0] > 192.5f);
  __syncthreads();
  red_s[tid] = pkb[tid] * lq_s[tid] + pkb[tid + 256] * lq_s[tid + 256];
  __syncthreads();
  for (int s = 128; s > 0; s >>= 1) { if (tid < s) red_s[tid] += red_s[tid + s]; __syncthreads(); }
  float pkbdot = red_s[0];
  __syncthreads();
  for (int n = wave; n < 193; n += 4) {
    const float* kr = kv + ((size_t)b * 193 + n) * 1024 + lane * 8;
    float4 a = *(const float4*)(kr);
    float4 c = *(const float4*)(kr + 4);
    const float* lq = lq_s + lane * 8;
    float dp = a.x * lq[0] + a.y * lq[1] + a.z * lq[2] + a.w * lq[3]
             + c.x * lq[4] + c.y * lq[5] + c.z * lq[6] + c.w * lq[7];
#pragma unroll
    for (int o = 1; o < 64; o <<= 1) dp += __shfl_xor(dp, o);
    if (lane == 0) {
      float sc = (dp + pkbdot) * 0.04419417382415922f;
      if (sm_s[n] && !allm) sc = FMIN_F;
      w_s[n] = sc;
    }
  }
  __syncthreads();
  float sc = w_s[tid];
  red_s[tid] = sc;
  __syncthreads();
  for (int s = 128; s > 0; s >>= 1) { if (tid < s) red_s[tid] = fmaxf(red_s[tid], red_s[tid + s]); __syncthreads(); }
  float mx = red_s[0];
  __syncthreads();
  float e = __expf(sc - mx);
  w_s[tid] = e;
  red_s[tid] = e;
  __syncthreads();
  for (int s = 128; s > 0; s >>= 1) { if (tid < s) red_s[tid] += red_s[tid + s]; __syncthreads(); }
  float invS = 1.f / red_s[0];
  __syncthreads();
  float o0 = 0.f, o1 = 0.f;
  const float* vbase = kv + (size_t)b * 193 * 1024 + 512;
#pragma unroll 4
  for (int n = 0; n < 193; ++n) {
    float w = w_s[n];
    const float* vr = vbase + (size_t)n * 1024;
    o0 += w * vr[tid];
    o1 += w * vr[tid + 256];
  }
  o0 = o0 * invS + pvb[tid];
  o1 = o1 * invS + pvb[tid + 256];
  red_s[tid] = o0 * o0 + o1 * o1;
  __syncthreads();
  for (int s = 128; s > 0; s >>= 1) { if (tid < s) red_s[tid] += red_s[tid + s]; __syncthreads(); }
  float scale = rsqrtf(red_s[0] * (1.f / 512.f) + 1e-6f);
  if (allm) scale = 0.f;
  out[((size_t)b * 16 + l) * 512 + tid] = o0 * scale * pnw[tid];
  out[((size_t)b * 16 + l) * 512 + tid + 256] = o1 * scale * pnw[tid + 256];
}

extern "C" void kernel_launch(void* const* d_in, const int* in_sizes, int n_in,
                              void* d_out, int out_size, void* d_ws, size_t ws_size,
                              hipStream_t stream) {
  (void)in_sizes; (void)n_in; (void)out_size; (void)ws_size;
  const float* tokens      = (const float*)d_in[0];
  const int*   lengths     = (const int*)d_in[1];
  const float* query       = (const float*)d_in[2];
  const float* comp_wv     = (const float*)d_in[3];
  const float* comp_bv     = (const float*)d_in[4];
  const float* comp_ww     = (const float*)d_in[5];
  const float* comp_bw     = (const float*)d_in[6];
  const float* comp_pos    = (const float*)d_in[7];
  const float* comp_norm_w = (const float*)d_in[8];
  const float* idx_qd_w    = (const float*)d_in[9];
  const float* idx_qd_b    = (const float*)d_in[10];
  const float* idx_qu_w    = (const float*)d_in[11];
  const float* idx_qu_b    = (const float*)d_in[12];
  const float* idx_k_w     = (const float*)d_in[13];
  const float* idx_k_b     = (const float*)d_in[14];
  const float* idx_hw_w    = (const float*)d_in[15];
  const float* idx_hw_b    = (const float*)d_in[16];
  const float* idx_qn_w    = (const float*)d_in[17];
  const float* idx_kn_w    = (const float*)d_in[18];
  const float* pool_latents= (const float*)d_in[19];
  const float* pool_q_w    = (const float*)d_in[20];
  const float* pool_q_b    = (const float*)d_in[21];
  const float* pool_k_w    = (const float*)d_in[22];
  const float* pool_k_b    = (const float*)d_in[23];
  const float* pool_v_w    = (const float*)d_in[24];
  const float* pool_v_b    = (const float*)d_in[25];
  const float* pool_norm_w = (const float*)d_in[26];

  char* ws = (char*)d_ws;
  // ws_size = 512 MB (measured via harness poison fill). Single-pass layout:
  unsigned short* A2    = (unsigned short*)(ws + 0);           // 128 MB [0, 134217728)
  float*          bt    = (float*)(ws + 0);                    // 4 MB   (alias, post-GEMM)
  float*          keys  = (float*)(ws + 4194304);              // 512 KB (alias)
  int*            idxs  = (int*)  (ws + 4718592);              // 2 KB   (alias)
  int*            smask = (int*)  (ws + 4720640);              // 8 KB   (alias)
  float*          qproj = (float*)(ws + 4728832);              // 16 KB  (alias)
  unsigned short* PW2   = (unsigned short*)(ws + 4745216);     // 1 MB   (alias)
  unsigned short* src_bf= (unsigned short*)(ws + 5793792);     // 1.7 MB (alias, 1664 rows)
  float*          kv    = (float*)(ws + 7497728);              // 6.8 MB (alias, 1664 rows)
  float*          gpart = (float*)(ws + 134217728);            // 8 MB  [134217728, 142606336)
  float*          ctx   = (float*)(ws + 142606336);            // 4 MB  [142606336, 146800640)
  unsigned short* W2    = (unsigned short*)(ws + 146800640);   // 2 MB  [146800640, 148897792)
  float*          gsum  = (float*)(ws + 148897792);            // 16 KB

  k_wsplit<<<dim3(8, 8, 2), 256, 0, stream>>>(comp_wv, comp_ww, W2);
  k_split<<<4096, 256, 0, stream>>>(tokens, lengths, A2, gpart);
  k_gemm128<<<dim3(512, 8), 256, 0, stream>>>(A2, W2, comp_bv, comp_bw,
                                              comp_pos, lengths, ctx);
  k_gred<<<dim3(8, 2), 256, 0, stream>>>(gpart, gsum);
  // A2 region free from here on
  k_wpool<<<dim3(8, 8, 2), 256, 0, stream>>>(pool_k_w, pool_v_w, PW2);
  k_btk<<<2048, 64, 0, stream>>>(ctx, comp_norm_w, idx_k_w, idx_k_b, idx_kn_w,
                                 bt, keys);
  k_sel<<<8, 256, 0, stream>>>(query, keys, lengths, idx_qd_w, idx_qd_b,
                               idx_qu_w, idx_qu_b, idx_hw_w, idx_hw_b,
                               idx_qn_w, idxs);
  k_src<<<dim3(8, 208), 128, 0, stream>>>(tokens, bt, gsum, lengths, idxs,
                                          src_bf, smask);
  k_kvm<<<dim3(13, 8), 256, 0, stream>>>(src_bf, PW2, kv);
  k_qproj<<<dim3(8, 2), 256, 0, stream>>>(query, pool_q_w, pool_q_b, qproj);
  k_attn<<<dim3(8, 16), 256, 0, stream>>>(kv, qproj, pool_latents, pool_k_b,
                                          pool_v_b, pool_norm_w, smask,
                                          (float*)d_out);
}

// Round 13
// 448.245 us; speedup vs baseline: 1.0162x; 1.0162x over previous
//
#include <hip/hip_runtime.h>
#include <stdint.h>

typedef __attribute__((ext_vector_type(8))) _Float16 half8;
typedef __attribute__((ext_vector_type(8))) short short8;
typedef __attribute__((ext_vector_type(4))) float f32x4;

#define FMIN_F (-3.4028234663852886e38f)

__device__ __forceinline__ unsigned short rne_bf16(float x) {
  unsigned u = __float_as_uint(x);
  unsigned r = (u + 0x7FFFu + ((u >> 16) & 1u)) >> 16;
  return (unsigned short)r;
}

__device__ __forceinline__ void split16(float x, unsigned short& h, unsigned short& l) {
  _Float16 hh = (_Float16)x;
  float r = x - (float)hh;
  _Float16 ll = (_Float16)r;
  union { _Float16 f; unsigned short u; } a, b;
  a.f = hh; b.f = ll;
  h = a.u; l = b.u;
}

__device__ __forceinline__ void glds16(const unsigned short* g, unsigned short* l) {
  __builtin_amdgcn_global_load_lds(
      (const __attribute__((address_space(1))) unsigned int*)g,
      (__attribute__((address_space(3))) unsigned int*)l, 16, 0, 0);
}

// ---- tokens f32 -> A2=[Ah|Al] rows + per-block partial column sums (NO atomics)
__global__ __launch_bounds__(256) void k_split(const float* __restrict__ tok,
    const int* __restrict__ lengths, unsigned short* __restrict__ A2,
    float* __restrict__ gpart) {
  __shared__ float ps[512];
  int wg = blockIdx.x, tid = threadIdx.x;
  int colv = tid & 127;
  int rh = tid >> 7;
  int r0 = wg << 4;                       // 16 rows per block
  int b0 = r0 >> 13;                      // batch
  int part = wg & 511;                    // block index within batch
  int len = lengths[b0];
  float sx = 0.f, sy = 0.f, sz = 0.f, sw = 0.f;
#pragma unroll
  for (int i = 0; i < 8; ++i) {
    int row = r0 + (i << 1) + rh;
    const float4 v = ((const float4*)(tok + (size_t)row * 512))[colv];
    ushort4 oh, ol;
    split16(v.x, oh.x, ol.x); split16(v.y, oh.y, ol.y);
    split16(v.z, oh.z, ol.z); split16(v.w, oh.w, ol.w);
    *(ushort4*)(A2 + (size_t)row * 1024 + colv * 4) = oh;
    *(ushort4*)(A2 + (size_t)row * 1024 + 512 + colv * 4) = ol;
    if ((row & 8191) < len) { sx += v.x; sy += v.y; sz += v.z; sw += v.w; }
  }
  if (rh == 0) {
    ps[colv * 4 + 0] = sx; ps[colv * 4 + 1] = sy;
    ps[colv * 4 + 2] = sz; ps[colv * 4 + 3] = sw;
  }
  __syncthreads();
  if (rh == 1) {
    ps[colv * 4 + 0] += sx; ps[colv * 4 + 1] += sy;
    ps[colv * 4 + 2] += sz; ps[colv * 4 + 3] += sw;
  }
  __syncthreads();
  float* gp = gpart + ((size_t)b0 * 512 + part) * 512;
  gp[tid] = ps[tid];
  gp[tid + 256] = ps[tid + 256];
}

// ---- reduce partials -> gsum[b][512]; grid (8,2) ------------------------------
__global__ __launch_bounds__(256) void k_gred(const float* __restrict__ gpart,
    float* __restrict__ gsum) {
  int b = blockIdx.x, half = blockIdx.y, tid = threadIdx.x;
  int c = half * 256 + tid;
  float a0 = 0.f;
  for (int part = 0; part < 512; ++part)
    a0 += gpart[((size_t)b * 512 + part) * 512 + c];
  gsum[b * 512 + c] = a0;
}

// ---- pack comp [Wv|Ww] transposed to W2 [1024][Wh(512)|Wl(512)] (coalesced) ---
__global__ __launch_bounds__(256) void k_wsplit(const float* __restrict__ wv,
    const float* __restrict__ ww, unsigned short* __restrict__ W2) {
  __shared__ float t[64][65];
  int kk0 = blockIdx.x * 64, d0 = blockIdx.y * 64, m = blockIdx.z;
  const float* W = m ? ww : wv;
  int tid = threadIdx.x;
  for (int i = tid; i < 4096; i += 256) {
    int k = i >> 6, d = i & 63;
    t[k][d] = W[(size_t)(kk0 + k) * 512 + d0 + d];
  }
  __syncthreads();
  int dr = tid >> 2, kq = tid & 3;
  int d = d0 + dr;
  int n = (d >> 5) * 64 + m * 32 + (d & 31);
  size_t baseH = (size_t)n * 1024 + kk0 + kq * 16;
  for (int q = 0; q < 16; ++q) {
    unsigned short hh, ll;
    split16(t[kq * 16 + q][dr], hh, ll);
    W2[baseH + q] = hh;
    W2[baseH + 512 + q] = ll;
  }
}

// ---- pack pool [Wk|Wv] transposed to PW2 [1024][512] bf16 ---------------------
__global__ __launch_bounds__(256) void k_wpool(const float* __restrict__ wk,
    const float* __restrict__ wv, unsigned short* __restrict__ PW) {
  __shared__ float t[64][65];
  int kk0 = blockIdx.x * 64, d0 = blockIdx.y * 64, m = blockIdx.z;
  const float* W = m ? wv : wk;
  int tid = threadIdx.x;
  for (int i = tid; i < 4096; i += 256) {
    int k = i >> 6, d = i & 63;
    t[k][d] = W[(size_t)(kk0 + k) * 512 + d0 + d];
  }
  __syncthreads();
  int dr = tid >> 2, kq = tid & 3;
  int n = m * 512 + d0 + dr;
  size_t base = (size_t)n * 512 + kk0 + kq * 16;
  for (int q = 0; q < 16; ++q)
    PW[base + q] = rne_bf16(t[kq * 16 + q][dr]);
}

// ---- 128x128-tile split-f16 GEMM + XOR-swizzled LDS ---------------------------
// grid (8, 512): x = ny (N-tile, FAST) so the 8 blocks sharing an A-panel are
// dispatch-adjacent (1/XCD, panel L3-hot); y = mt (M-tile) streams A sequentially.
__global__ __launch_bounds__(256) void k_gemm128(
    const unsigned short* __restrict__ A2, const unsigned short* __restrict__ W2,
    const float* __restrict__ bv, const float* __restrict__ bw,
    const float* __restrict__ cpos, const int* __restrict__ lengths,
    float* __restrict__ ctx) {
  __shared__ __align__(16) unsigned short Ash[128 * 64];
  __shared__ __align__(16) unsigned short Asl[128 * 64];
  __shared__ __align__(16) unsigned short Bsh[128 * 64];
  __shared__ __align__(16) unsigned short Bsl[128 * 64];
  __shared__ float pos_s[32 * 64];
  int ny = blockIdx.x, mt = blockIdx.y;
  int tid = threadIdx.x;
  int wave = tid >> 6, lane = tid & 63;
  int m0 = mt << 7, n0 = ny << 7;
  for (int i = tid; i < 2048; i += 256) {
    int s = i >> 6, c = i & 63;
    pos_s[i] = cpos[s * 512 + ny * 64 + c];
  }
  f32x4 acc[4][4];
#pragma unroll
  for (int i = 0; i < 4; ++i)
#pragma unroll
    for (int j = 0; j < 4; ++j) acc[i][j] = (f32x4){0.f, 0.f, 0.f, 0.f};
  int lrow = lane >> 3, lcol = lane & 7;
  int wm = wave >> 1, wn = wave & 1;
  int l15 = lane & 15, lg4 = lane >> 4;
  int scs_ = (lcol ^ lrow) * 8;     // swizzled source chunk; LDS dest stays linear
  int rx = (l15 & 7);               // read-side row XOR key
  for (int kk = 0; kk < 8; ++kk) {
    int k0 = kk << 6;
#pragma unroll
    for (int j = 0; j < 4; ++j) {
      int r = wave * 32 + j * 8 + lrow;
      size_t ga = (size_t)(m0 + r) * 1024 + k0 + scs_;
      size_t gb = (size_t)(n0 + r) * 1024 + k0 + scs_;
      int ls = r * 64 + lcol * 8;
      glds16(A2 + ga, Ash + ls);
      glds16(A2 + ga + 512, Asl + ls);
      glds16(W2 + gb, Bsh + ls);
      glds16(W2 + gb + 512, Bsl + ls);
    }
    __syncthreads();
#pragma unroll
    for (int ks = 0; ks < 2; ++ks) {
      int cofs = ((ks * 4 + lg4) ^ rx) * 8;   // XOR-swizzled read offset
      half8 bh[4], bl[4];
#pragma unroll
      for (int i = 0; i < 4; ++i) {
        bh[i] = *(const half8*)(Bsh + (wn * 64 + i * 16 + l15) * 64 + cofs);
        bl[i] = *(const half8*)(Bsl + (wn * 64 + i * 16 + l15) * 64 + cofs);
      }
#pragma unroll
      for (int mi = 0; mi < 4; ++mi) {
        half8 ah = *(const half8*)(Ash + (wm * 64 + mi * 16 + l15) * 64 + cofs);
        half8 al = *(const half8*)(Asl + (wm * 64 + mi * 16 + l15) * 64 + cofs);
#pragma unroll
        for (int ni = 0; ni < 4; ++ni) {
          acc[mi][ni] = __builtin_amdgcn_mfma_f32_16x16x32_f16(ah, bh[ni], acc[mi][ni], 0, 0, 0);
          acc[mi][ni] = __builtin_amdgcn_mfma_f32_16x16x32_f16(al, bh[ni], acc[mi][ni], 0, 0, 0);
          acc[mi][ni] = __builtin_amdgcn_mfma_f32_16x16x32_f16(ah, bl[ni], acc[mi][ni], 0, 0, 0);
        }
      }
    }
    __syncthreads();
  }
  // epilogue: per (32-token block, d): softmax over s of logits, weighted value sum
  int bidx = m0 >> 13;
  int len = lengths[bidx];
#pragma unroll
  for (int niv = 0; niv < 2; ++niv) {
    int d = (ny * 2 + wn) * 32 + niv * 16 + l15;   // global d in [0,512)
    int dloc = wn * 32 + niv * 16 + l15;           // wg-local d in [0,64)
    float bwv = bw[d], bvv = bv[d];
#pragma unroll
    for (int blk = 0; blk < 2; ++blk) {
      int growL = m0 + wm * 64 + blk * 32;
      int nb = (growL & 8191) >> 5;
      int vcnt = min(max(len - nb * 32, 0), 32);
      float lg[8], vl[8];
      float mx = FMIN_F;
#pragma unroll
      for (int j = 0; j < 8; ++j) {
        int mi = blk * 2 + (j >> 2);
        int r = j & 3;
        int s = ((j >> 2) << 4) + lg4 * 4 + r;
        float L = acc[mi][2 + niv][r] + bwv + pos_s[s * 64 + dloc];
        float V = acc[mi][niv][r] + bvv;
        lg[j] = L; vl[j] = V;
        if (s < vcnt) mx = fmaxf(mx, L);
      }
      mx = fmaxf(mx, __shfl_xor(mx, 16));
      mx = fmaxf(mx, __shfl_xor(mx, 32));
      float num = 0.f, den = 0.f;
#pragma unroll
      for (int j = 0; j < 8; ++j) {
        int s = ((j >> 2) << 4) + lg4 * 4 + (j & 3);
        if (s < vcnt) {
          float e = __expf(lg[j] - mx);
          num += e * vl[j];
          den += e;
        }
      }
      num += __shfl_xor(num, 16); num += __shfl_xor(num, 32);
      den += __shfl_xor(den, 16); den += __shfl_xor(den, 32);
      float o = (den > 0.f) ? (num / den) : 0.f;
      if (lg4 == 0)
        ctx[((size_t)bidx * 256 + nb) * 512 + d] = o;
    }
  }
}

// ---- fused: rmsnorm(ctx) -> bt  AND  keys = rmsnorm(bt @ idx_k_w + kb, kn) ----
__global__ __launch_bounds__(64) void k_btk(const float* __restrict__ ctx,
    const float* __restrict__ nw, const float* __restrict__ kw,
    const float* __restrict__ kb, const float* __restrict__ knw,
    float* __restrict__ bt, float* __restrict__ keys) {
  int row = blockIdx.x, lane = threadIdx.x;
  __shared__ float bs[512];
  const float* cp = ctx + (size_t)row * 512 + lane * 8;
  float x[8];
#pragma unroll
  for (int j = 0; j < 8; ++j) x[j] = cp[j];
  float ss = 0.f;
#pragma unroll
  for (int j = 0; j < 8; ++j) ss += x[j] * x[j];
#pragma unroll
  for (int o = 1; o < 64; o <<= 1) ss += __shfl_xor(ss, o);
  float sc = rsqrtf(ss * (1.f / 512.f) + 1e-6f);
  float* op = bt + (size_t)row * 512 + lane * 8;
  const float* nwp = nw + lane * 8;
#pragma unroll
  for (int j = 0; j < 8; ++j) {
    float y = x[j] * sc * nwp[j];
    op[j] = y;
    bs[lane * 8 + j] = y;
  }
  __syncthreads();
  float a = kb[lane];
  for (int k = 0; k < 512; ++k) a += bs[k] * kw[k * 64 + lane];
  float s2 = a * a;
#pragma unroll
  for (int o = 1; o < 64; o <<= 1) s2 += __shfl_xor(s2, o);
  keys[(size_t)row * 64 + lane] = a * rsqrtf(s2 * (1.f / 64.f) + 1e-6f) * knw[lane];
}

// ---- per-b: ql, qh, hw, scores, top-64 (keys staged in LDS, padded stride) ----
__global__ __launch_bounds__(256) void k_sel(
    const float* __restrict__ query, const float* __restrict__ keys,
    const int* __restrict__ lengths,
    const float* __restrict__ qdw, const float* __restrict__ qdb,
    const float* __restrict__ quw, const float* __restrict__ qub,
    const float* __restrict__ hww, const float* __restrict__ hwb,
    const float* __restrict__ qnw, int* __restrict__ idxs) {
  int b = blockIdx.x, tid = threadIdx.x;
  __shared__ float qs[512], qls[64], qhs[512], hws[8], scs[256];
  __shared__ float ks_s[256 * 65];        // padded: conflict-free
  int wave = tid >> 6, lane = tid & 63;
  {
    const float* kb_g = keys + (size_t)b * 256 * 64;
    for (int r = wave; r < 256; r += 4)
      ks_s[r * 65 + lane] = kb_g[r * 64 + lane];
  }
  for (int i = tid; i < 512; i += 256) qs[i] = query[b * 512 + i];
  __syncthreads();
  if (tid < 64) {
    float a = qdb[tid];
    for (int k = 0; k < 512; ++k) a += qs[k] * qdw[k * 64 + tid];
    float ss = a * a;
#pragma unroll
    for (int o = 1; o < 64; o <<= 1) ss += __shfl_xor(ss, o);
    qls[tid] = a * rsqrtf(ss * (1.f / 64.f) + 1e-6f) * qnw[tid];
  }
  __syncthreads();
  for (int j = tid; j < 512; j += 256) {
    float a = qub[j];
    for (int k = 0; k < 64; ++k) a += qls[k] * quw[k * 512 + j];
    qhs[j] = a;
  }
  if (tid < 8) {
    float a = hwb[tid];
    for (int k = 0; k < 512; ++k) a += qs[k] * hww[k * 8 + tid];
    hws[tid] = a;
  }
  __syncthreads();
  if (tid == 0) {
    float m = hws[0];
    for (int h = 1; h < 8; ++h) m = fmaxf(m, hws[h]);
    float s = 0.f, e[8];
    for (int h = 0; h < 8; ++h) { e[h] = __expf(hws[h] - m); s += e[h]; }
    for (int h = 0; h < 8; ++h) hws[h] = e[h] / s;
  }
  __syncthreads();
  {
    int len = lengths[b];
    int n = tid;
    float sc = FMIN_F;
    if (n * 32 < len) {
      sc = 0.f;
      const float* kr = ks_s + n * 65;
      for (int h = 0; h < 8; ++h) {
        float dp = 0.f;
#pragma unroll
        for (int i = 0; i < 64; ++i) dp += qhs[h * 64 + i] * kr[i];
        sc += fmaxf(dp, 0.f) * hws[h];
      }
    }
    scs[n] = sc;
  }
  __syncthreads();
  if (tid < 64) {
    unsigned long long kk[4];
#pragma unroll
    for (int j = 0; j < 4; ++j) {
      int n = j * 64 + tid;
      unsigned u = __float_as_uint(scs[n]);
      u = (u & 0x80000000u) ? ~u : (u | 0x80000000u);
      kk[j] = ((unsigned long long)u << 32) | (unsigned long long)(255 - n);
    }
    for (int r = 0; r < 64; ++r) {
      unsigned long long m = kk[0];
      if (kk[1] > m) m = kk[1];
      if (kk[2] > m) m = kk[2];
      if (kk[3] > m) m = kk[3];
#pragma unroll
      for (int o = 1; o < 64; o <<= 1) {
        unsigned long long t = __shfl_xor(m, o);
        if (t > m) m = t;
      }
      if (tid == 0) idxs[b * 64 + r] = 255 - (int)(m & 0xFFull);
#pragma unroll
      for (int j = 0; j < 4; ++j) if (kk[j] == m) kk[j] = 0ull;
    }
  }
}

// ---- assemble src rows (recent | sel | gtok) as bf16 + smask + zero pad rows --
__global__ __launch_bounds__(128) void k_src(const float* __restrict__ tok,
    const float* __restrict__ bt, const float* __restrict__ gsum,
    const int* __restrict__ lengths, const int* __restrict__ idxs,
    unsigned short* __restrict__ src_bf, int* __restrict__ smask) {
  int b = blockIdx.x, n = blockIdx.y, tid = threadIdx.x;
  int d0 = tid * 4;
  if (n >= 193) {   // zero a pad row (rows 1544..1663 of the 1664-row buffer)
    size_t prow = 1544 + (size_t)b * 15 + (n - 193);
    ushort4 z; z.x = 0; z.y = 0; z.z = 0; z.w = 0;
    *(ushort4*)(src_bf + prow * 512 + d0) = z;
    return;
  }
  int len = lengths[b];
  float v0 = 0.f, v1 = 0.f, v2 = 0.f, v3 = 0.f;
  int sm = 0;
  if (n < 128) {
    int cl = min(max(len, 0), 8192);
    int start = max(cl - 128, 0);
    int pos = min(start + n, 8191);
    bool vis = n < min(cl, 128);
    sm = vis ? 0 : 1;
    if (vis) {
      const float* tp = tok + ((size_t)b * 8192 + pos) * 512 + d0;
      float pn = (float)n;
#pragma unroll
      for (int j = 0; j < 4; ++j) {
        int d = d0 + j;
        int i = d >> 1;
        float ang = pn * __expf(-9.210340371976184f * ((float)i * (1.f / 256.f)));
        float pe = (d & 1) ? cosf(ang) : sinf(ang);
        float t = tp[j] + pe;
        if (j == 0) v0 = t; else if (j == 1) v1 = t; else if (j == 2) v2 = t; else v3 = t;
      }
    }
  } else if (n < 192) {
    int idx = idxs[b * 64 + (n - 128)];
    sm = (idx * 32 >= len) ? 1 : 0;
    const float* bp = bt + ((size_t)b * 256 + idx) * 512 + d0;
    v0 = bp[0]; v1 = bp[1]; v2 = bp[2]; v3 = bp[3];
  } else {
    sm = 0;
    float inv = 1.f / (float)max(len, 1);
    const float* gp = gsum + b * 512 + d0;
    v0 = gp[0] * inv; v1 = gp[1] * inv; v2 = gp[2] * inv; v3 = gp[3] * inv;
  }
  ushort4 o;
  o.x = rne_bf16(v0); o.y = rne_bf16(v1); o.z = rne_bf16(v2); o.w = rne_bf16(v3);
  *(ushort4*)(src_bf + ((size_t)b * 193 + n) * 512 + d0) = o;
  if (tid == 0) smask[b * 193 + n] = sm;
}

// ---- pooling k/v GEMM (bf16 MFMA): kv[r][0:512]=src@Wk, [512:1024]=src@Wv -----
__global__ __launch_bounds__(256) void k_kvm(
    const unsigned short* __restrict__ src_bf, const unsigned short* __restrict__ PW,
    float* __restrict__ kv) {
  __shared__ __align__(16) unsigned short As[128 * 64];
  __shared__ __align__(16) unsigned short Bs[128 * 64];
  int m0 = blockIdx.x << 7, n0 = blockIdx.y << 7;
  int tid = threadIdx.x;
  int wave = tid >> 6, lane = tid & 63;
  int wm = wave >> 1, wn = wave & 1;
  int l15 = lane & 15, lg4 = lane >> 4;
  int lrow = lane >> 3, lcol = lane & 7;
  f32x4 acc[4][4];
#pragma unroll
  for (int i = 0; i < 4; ++i)
#pragma unroll
    for (int j = 0; j < 4; ++j) acc[i][j] = (f32x4){0.f, 0.f, 0.f, 0.f};
  for (int kk = 0; kk < 8; ++kk) {
    int k0 = kk << 6;
#pragma unroll
    for (int j = 0; j < 4; ++j) {
      int r = wave * 32 + j * 8 + lrow;
      glds16(src_bf + (size_t)(m0 + r) * 512 + k0 + lcol * 8, As + r * 64 + lcol * 8);
      glds16(PW + (size_t)(n0 + r) * 512 + k0 + lcol * 8, Bs + r * 64 + lcol * 8);
    }
    __syncthreads();
#pragma unroll
    for (int ks = 0; ks < 2; ++ks) {
      int kb = ks * 32 + lg4 * 8;
      short8 av[4], bf[4];
#pragma unroll
      for (int i = 0; i < 4; ++i) {
        av[i] = *(const short8*)(As + (wm * 64 + i * 16 + l15) * 64 + kb);
        bf[i] = *(const short8*)(Bs + (wn * 64 + i * 16 + l15) * 64 + kb);
      }
#pragma unroll
      for (int mi = 0; mi < 4; ++mi)
#pragma unroll
        for (int ni = 0; ni < 4; ++ni)
          acc[mi][ni] = __builtin_amdgcn_mfma_f32_16x16x32_bf16(av[mi], bf[ni], acc[mi][ni], 0, 0, 0);
    }
    __syncthreads();
  }
#pragma unroll
  for (int mi = 0; mi < 4; ++mi)
#pragma unroll
    for (int ni = 0; ni < 4; ++ni)
#pragma unroll
      for (int rr = 0; rr < 4; ++rr) {
        int grow = m0 + wm * 64 + mi * 16 + lg4 * 4 + rr;
        kv[(size_t)grow * 1024 + n0 + wn * 64 + ni * 16 + l15] = acc[mi][ni][rr];
      }
}

// ---- qproj = query @ pool_q_w + pool_q_b (direct) -----------------------------
__global__ __launch_bounds__(256) void k_qproj(const float* __restrict__ query,
    const float* __restrict__ pqw, const float* __restrict__ pqb,
    float* __restrict__ qp) {
  int b = blockIdx.x;
  int c = blockIdx.y * 256 + threadIdx.x;
  __shared__ float qs[512];
  for (int i = threadIdx.x; i < 512; i += 256) qs[i] = query[b * 512 + i];
  __syncthreads();
  float a = pqb[c];
  for (int k = 0; k < 512; ++k) a += qs[k] * pqw[(size_t)k * 512 + c];
  qp[b * 512 + c] = a;
}

// ---- latent cross-attention + rmsnorm -> out (coalesced, branchless PV) -------
__global__ __launch_bounds__(256) void k_attn(const float* __restrict__ kv,
    const float* __restrict__ qproj, const float* __restrict__ latents,
    const float* __restrict__ pkb, const float* __restrict__ pvb,
    const float* __restrict__ pnw, const int* __restrict__ smask,
    float* __restrict__ out) {
  int b = blockIdx.x, l = blockIdx.y, tid = threadIdx.x;
  int wave = tid >> 6, lane = tid & 63;
  __shared__ float lq_s[512];
  __shared__ float w_s[256];
  __shared__ float red_s[256];
  __shared__ int sm_s[256];
  for (int i = tid; i < 512; i += 256) lq_s[i] = latents[l * 512 + i] + qproj[b * 512 + i];
  sm_s[tid] = (tid < 193) ? smask[b * 193 + tid] : 1;
  w_s[tid] = FMIN_F;
  __syncthreads();
  red_s[tid] = (tid < 193 && sm_s[tid]) ? 1.f : 0.f;
  __syncthreads();
  for (int s = 128; s > 0; s >>= 1) { if (tid < s) red_s[tid] += red_s[tid + s]; __syncthreads(); }
  bool allm = (red_s[0] > 192.5f);
  __syncthreads();
  red_s[tid] = pkb[tid] * lq_s[tid] + pkb[tid + 256] * lq_s[tid + 256];
  __syncthreads();
  for (int s = 128; s > 0; s >>= 1) { if (tid < s) red_s[tid] += red_s[tid + s]; __syncthreads(); }
  float pkbdot = red_s[0];
  __syncthreads();
  for (int n = wave; n < 193; n += 4) {
    const float* kr = kv + ((size_t)b * 193 + n) * 1024 + lane * 8;
    float4 a = *(const float4*)(kr);
    float4 c = *(const float4*)(kr + 4);
    const float* lq = lq_s + lane * 8;
    float dp = a.x * lq[0] + a.y * lq[1] + a.z * lq[2] + a.w * lq[3]
             + c.x * lq[4] + c.y * lq[5] + c.z * lq[6] + c.w * lq[7];
#pragma unroll
    for (int o = 1; o < 64; o <<= 1) dp += __shfl_xor(dp, o);
    if (lane == 0) {
      float sc = (dp + pkbdot) * 0.04419417382415922f;
      if (sm_s[n] && !allm) sc = FMIN_F;
      w_s[n] = sc;
    }
  }
  __syncthreads();
  float sc = w_s[tid];
  red_s[tid] = sc;
  __syncthreads();
  for (int s = 128; s > 0; s >>= 1) { if (tid < s) red_s[tid] = fmaxf(red_s[tid], red_s[tid + s]); __syncthreads(); }
  float mx = red_s[0];
  __syncthreads();
  float e = __expf(sc - mx);
  w_s[tid] = e;
  red_s[tid] = e;
  __syncthreads();
  for (int s = 128; s > 0; s >>= 1) { if (tid < s) red_s[tid] += red_s[tid + s]; __syncthreads(); }
  float invS = 1.f / red_s[0];
  __syncthreads();
  float o0 = 0.f, o1 = 0.f;
  const float* vbase = kv + (size_t)b * 193 * 1024 + 512;
#pragma unroll 4
  for (int n = 0; n < 193; ++n) {
    float w = w_s[n];
    const float* vr = vbase + (size_t)n * 1024;
    o0 += w * vr[tid];
    o1 += w * vr[tid + 256];
  }
  o0 = o0 * invS + pvb[tid];
  o1 = o1 * invS + pvb[tid + 256];
  red_s[tid] = o0 * o0 + o1 * o1;
  __syncthreads();
  for (int s = 128; s > 0; s >>= 1) { if (tid < s) red_s[tid] += red_s[tid + s]; __syncthreads(); }
  float scale = rsqrtf(red_s[0] * (1.f / 512.f) + 1e-6f);
  if (allm) scale = 0.f;
  out[((size_t)b * 16 + l) * 512 + tid] = o0 * scale * pnw[tid];
  out[((size_t)b * 16 + l) * 512 + tid + 256] = o1 * scale * pnw[tid + 256];
}

extern "C" void kernel_launch(void* const* d_in, const int* in_sizes, int n_in,
                              void* d_out, int out_size, void* d_ws, size_t ws_size,
                              hipStream_t stream) {
  (void)in_sizes; (void)n_in; (void)out_size; (void)ws_size;
  const float* tokens      = (const float*)d_in[0];
  const int*   lengths     = (const int*)d_in[1];
  const float* query       = (const float*)d_in[2];
  const float* comp_wv     = (const float*)d_in[3];
  const float* comp_bv     = (const float*)d_in[4];
  const float* comp_ww     = (const float*)d_in[5];
  const float* comp_bw     = (const float*)d_in[6];
  const float* comp_pos    = (const float*)d_in[7];
  const float* comp_norm_w = (const float*)d_in[8];
  const float* idx_qd_w    = (const float*)d_in[9];
  const float* idx_qd_b    = (const float*)d_in[10];
  const float* idx_qu_w    = (const float*)d_in[11];
  const float* idx_qu_b    = (const float*)d_in[12];
  const float* idx_k_w     = (const float*)d_in[13];
  const float* idx_k_b     = (const float*)d_in[14];
  const float* idx_hw_w    = (const float*)d_in[15];
  const float* idx_hw_b    = (const float*)d_in[16];
  const float* idx_qn_w    = (const float*)d_in[17];
  const float* idx_kn_w    = (const float*)d_in[18];
  const float* pool_latents= (const float*)d_in[19];
  const float* pool_q_w    = (const float*)d_in[20];
  const float* pool_q_b    = (const float*)d_in[21];
  const float* pool_k_w    = (const float*)d_in[22];
  const float* pool_k_b    = (const float*)d_in[23];
  const float* pool_v_w    = (const float*)d_in[24];
  const float* pool_v_b    = (const float*)d_in[25];
  const float* pool_norm_w = (const float*)d_in[26];

  char* ws = (char*)d_ws;
  unsigned short* A2    = (unsigned short*)(ws + 0);           // 128 MB [0, 134217728)
  float*          bt    = (float*)(ws + 0);                    // 4 MB   (alias, post-GEMM)
  float*          keys  = (float*)(ws + 4194304);              // 512 KB (alias)
  int*            idxs  = (int*)  (ws + 4718592);              // 2 KB   (alias)
  int*            smask = (int*)  (ws + 4720640);              // 8 KB   (alias)
  float*          qproj = (float*)(ws + 4728832);              // 16 KB  (alias)
  unsigned short* PW2   = (unsigned short*)(ws + 4745216);     // 1 MB   (alias)
  unsigned short* src_bf= (unsigned short*)(ws + 5793792);     // 1.7 MB (alias, 1664 rows)
  float*          kv    = (float*)(ws + 7497728);              // 6.8 MB (alias, 1664 rows)
  float*          gpart = (float*)(ws + 134217728);            // 8 MB
  float*          ctx   = (float*)(ws + 142606336);            // 4 MB
  unsigned short* W2    = (unsigned short*)(ws + 146800640);   // 2 MB
  float*          gsum  = (float*)(ws + 148897792);            // 16 KB

  k_wsplit<<<dim3(8, 8, 2), 256, 0, stream>>>(comp_wv, comp_ww, W2);
  k_split<<<4096, 256, 0, stream>>>(tokens, lengths, A2, gpart);
  k_gemm128<<<dim3(8, 512), 256, 0, stream>>>(A2, W2, comp_bv, comp_bw,
                                              comp_pos, lengths, ctx);
  k_gred<<<dim3(8, 2), 256, 0, stream>>>(gpart, gsum);
  // A2 region free from here on
  k_wpool<<<dim3(8, 8, 2), 256, 0, stream>>>(pool_k_w, pool_v_w, PW2);
  k_btk<<<2048, 64, 0, stream>>>(ctx, comp_norm_w, idx_k_w, idx_k_b, idx_kn_w,
                                 bt, keys);
  k_sel<<<8, 256, 0, stream>>>(query, keys, lengths, idx_qd_w, idx_qd_b,
                               idx_qu_w, idx_qu_b, idx_hw_w, idx_hw_b,
                               idx_qn_w, idxs);
  k_src<<<dim3(8, 208), 128, 0, stream>>>(tokens, bt, gsum, lengths, idxs,
                                          src_bf, smask);
  k_kvm<<<dim3(13, 8), 256, 0, stream>>>(src_bf, PW2, kv);
  k_qproj<<<dim3(8, 2), 256, 0, stream>>>(query, pool_q_w, pool_q_b, qproj);
  k_attn<<<dim3(8, 16), 256, 0, stream>>>(kv, qproj, pool_latents, pool_k_b,
                                          pool_v_b, pool_norm_w, smask,
                                          (float*)d_out);
}

// Round 14
// 424.971 us; speedup vs baseline: 1.0719x; 1.0548x over previous
//
#include <hip/hip_runtime.h>
#include <stdint.h>

typedef __attribute__((ext_vector_type(8))) _Float16 half8;
typedef __attribute__((ext_vector_type(8))) short short8;
typedef __attribute__((ext_vector_type(4))) float f32x4;

#define FMIN_F (-3.4028234663852886e38f)

__device__ __forceinline__ unsigned short rne_bf16(float x) {
  unsigned u = __float_as_uint(x);
  unsigned r = (u + 0x7FFFu + ((u >> 16) & 1u)) >> 16;
  return (unsigned short)r;
}

__device__ __forceinline__ void split16(float x, unsigned short& h, unsigned short& l) {
  _Float16 hh = (_Float16)x;
  float r = x - (float)hh;
  _Float16 ll = (_Float16)r;
  union { _Float16 f; unsigned short u; } a, b;
  a.f = hh; b.f = ll;
  h = a.u; l = b.u;
}

__device__ __forceinline__ void glds16(const unsigned short* g, unsigned short* l) {
  __builtin_amdgcn_global_load_lds(
      (const __attribute__((address_space(1))) unsigned int*)g,
      (__attribute__((address_space(3))) unsigned int*)l, 16, 0, 0);
}

// ---- tokens f32 -> A2=[Ah|Al] rows + per-block partial column sums (NO atomics)
__global__ __launch_bounds__(256) void k_split(const float* __restrict__ tok,
    const int* __restrict__ lengths, unsigned short* __restrict__ A2,
    float* __restrict__ gpart) {
  __shared__ float ps[512];
  int wg = blockIdx.x, tid = threadIdx.x;
  int colv = tid & 127;
  int rh = tid >> 7;
  int r0 = wg << 4;                       // 16 rows per block
  int b0 = r0 >> 13;                      // batch
  int part = wg & 511;                    // block index within batch
  int len = lengths[b0];
  float sx = 0.f, sy = 0.f, sz = 0.f, sw = 0.f;
#pragma unroll
  for (int i = 0; i < 8; ++i) {
    int row = r0 + (i << 1) + rh;
    const float4 v = ((const float4*)(tok + (size_t)row * 512))[colv];
    ushort4 oh, ol;
    split16(v.x, oh.x, ol.x); split16(v.y, oh.y, ol.y);
    split16(v.z, oh.z, ol.z); split16(v.w, oh.w, ol.w);
    *(ushort4*)(A2 + (size_t)row * 1024 + colv * 4) = oh;
    *(ushort4*)(A2 + (size_t)row * 1024 + 512 + colv * 4) = ol;
    if ((row & 8191) < len) { sx += v.x; sy += v.y; sz += v.z; sw += v.w; }
  }
  if (rh == 0) {
    ps[colv * 4 + 0] = sx; ps[colv * 4 + 1] = sy;
    ps[colv * 4 + 2] = sz; ps[colv * 4 + 3] = sw;
  }
  __syncthreads();
  if (rh == 1) {
    ps[colv * 4 + 0] += sx; ps[colv * 4 + 1] += sy;
    ps[colv * 4 + 2] += sz; ps[colv * 4 + 3] += sw;
  }
  __syncthreads();
  float* gp = gpart + ((size_t)b0 * 512 + part) * 512;
  gp[tid] = ps[tid];
  gp[tid + 256] = ps[tid + 256];
}

// ---- reduce partials -> gsum[b][512]; grid (8,2) ------------------------------
__global__ __launch_bounds__(256) void k_gred(const float* __restrict__ gpart,
    float* __restrict__ gsum) {
  int b = blockIdx.x, half = blockIdx.y, tid = threadIdx.x;
  int c = half * 256 + tid;
  float a0 = 0.f;
  for (int part = 0; part < 512; ++part)
    a0 += gpart[((size_t)b * 512 + part) * 512 + c];
  gsum[b * 512 + c] = a0;
}

// ---- pack comp [Wv|Ww] transposed to W2 [1024][Wh(512)|Wl(512)] (coalesced) ---
__global__ __launch_bounds__(256) void k_wsplit(const float* __restrict__ wv,
    const float* __restrict__ ww, unsigned short* __restrict__ W2) {
  __shared__ float t[64][65];
  int kk0 = blockIdx.x * 64, d0 = blockIdx.y * 64, m = blockIdx.z;
  const float* W = m ? ww : wv;
  int tid = threadIdx.x;
  for (int i = tid; i < 4096; i += 256) {
    int k = i >> 6, d = i & 63;
    t[k][d] = W[(size_t)(kk0 + k) * 512 + d0 + d];
  }
  __syncthreads();
  int dr = tid >> 2, kq = tid & 3;
  int d = d0 + dr;
  int n = (d >> 5) * 64 + m * 32 + (d & 31);
  size_t baseH = (size_t)n * 1024 + kk0 + kq * 16;
  for (int q = 0; q < 16; ++q) {
    unsigned short hh, ll;
    split16(t[kq * 16 + q][dr], hh, ll);
    W2[baseH + q] = hh;
    W2[baseH + 512 + q] = ll;
  }
}

// ---- pack pool [Wk|Wv] transposed to PW2 [1024][512] bf16 ---------------------
__global__ __launch_bounds__(256) void k_wpool(const float* __restrict__ wk,
    const float* __restrict__ wv, unsigned short* __restrict__ PW) {
  __shared__ float t[64][65];
  int kk0 = blockIdx.x * 64, d0 = blockIdx.y * 64, m = blockIdx.z;
  const float* W = m ? wv : wk;
  int tid = threadIdx.x;
  for (int i = tid; i < 4096; i += 256) {
    int k = i >> 6, d = i & 63;
    t[k][d] = W[(size_t)(kk0 + k) * 512 + d0 + d];
  }
  __syncthreads();
  int dr = tid >> 2, kq = tid & 3;
  int n = m * 512 + d0 + dr;
  size_t base = (size_t)n * 512 + kk0 + kq * 16;
  for (int q = 0; q < 16; ++q)
    PW[base + q] = rne_bf16(t[kq * 16 + q][dr]);
}

// ---- 128x128-tile split-f16 GEMM + XOR-swizzled LDS + XCD-local A-panels ------
// grid (8, 512). Linear bid = x + 8y -> XCD = bid%8 = x (round-robin assumption).
// ny = y&7, mt = x*64 + (y>>3): the 8 blocks sharing an A-panel (same mt) are
// y-consecutive at fixed x -> SAME XCD, back-to-back -> panel hits that XCD's L2.
__global__ __launch_bounds__(256) void k_gemm128(
    const unsigned short* __restrict__ A2, const unsigned short* __restrict__ W2,
    const float* __restrict__ bv, const float* __restrict__ bw,
    const float* __restrict__ cpos, const int* __restrict__ lengths,
    float* __restrict__ ctx) {
  __shared__ __align__(16) unsigned short Ash[128 * 64];
  __shared__ __align__(16) unsigned short Asl[128 * 64];
  __shared__ __align__(16) unsigned short Bsh[128 * 64];
  __shared__ __align__(16) unsigned short Bsl[128 * 64];
  __shared__ float pos_s[32 * 64];
  int ny = blockIdx.y & 7;
  int mt = blockIdx.x * 64 + (blockIdx.y >> 3);
  int tid = threadIdx.x;
  int wave = tid >> 6, lane = tid & 63;
  int m0 = mt << 7, n0 = ny << 7;
  for (int i = tid; i < 2048; i += 256) {
    int s = i >> 6, c = i & 63;
    pos_s[i] = cpos[s * 512 + ny * 64 + c];
  }
  f32x4 acc[4][4];
#pragma unroll
  for (int i = 0; i < 4; ++i)
#pragma unroll
    for (int j = 0; j < 4; ++j) acc[i][j] = (f32x4){0.f, 0.f, 0.f, 0.f};
  int lrow = lane >> 3, lcol = lane & 7;
  int wm = wave >> 1, wn = wave & 1;
  int l15 = lane & 15, lg4 = lane >> 4;
  int scs_ = (lcol ^ lrow) * 8;     // swizzled source chunk; LDS dest stays linear
  int rx = (l15 & 7);               // read-side row XOR key
  for (int kk = 0; kk < 8; ++kk) {
    int k0 = kk << 6;
#pragma unroll
    for (int j = 0; j < 4; ++j) {
      int r = wave * 32 + j * 8 + lrow;
      size_t ga = (size_t)(m0 + r) * 1024 + k0 + scs_;
      size_t gb = (size_t)(n0 + r) * 1024 + k0 + scs_;
      int ls = r * 64 + lcol * 8;
      glds16(A2 + ga, Ash + ls);
      glds16(A2 + ga + 512, Asl + ls);
      glds16(W2 + gb, Bsh + ls);
      glds16(W2 + gb + 512, Bsl + ls);
    }
    __syncthreads();
#pragma unroll
    for (int ks = 0; ks < 2; ++ks) {
      int cofs = ((ks * 4 + lg4) ^ rx) * 8;   // XOR-swizzled read offset
      half8 bh[4], bl[4];
#pragma unroll
      for (int i = 0; i < 4; ++i) {
        bh[i] = *(const half8*)(Bsh + (wn * 64 + i * 16 + l15) * 64 + cofs);
        bl[i] = *(const half8*)(Bsl + (wn * 64 + i * 16 + l15) * 64 + cofs);
      }
#pragma unroll
      for (int mi = 0; mi < 4; ++mi) {
        half8 ah = *(const half8*)(Ash + (wm * 64 + mi * 16 + l15) * 64 + cofs);
        half8 al = *(const half8*)(Asl + (wm * 64 + mi * 16 + l15) * 64 + cofs);
#pragma unroll
        for (int ni = 0; ni < 4; ++ni) {
          acc[mi][ni] = __builtin_amdgcn_mfma_f32_16x16x32_f16(ah, bh[ni], acc[mi][ni], 0, 0, 0);
          acc[mi][ni] = __builtin_amdgcn_mfma_f32_16x16x32_f16(al, bh[ni], acc[mi][ni], 0, 0, 0);
          acc[mi][ni] = __builtin_amdgcn_mfma_f32_16x16x32_f16(ah, bl[ni], acc[mi][ni], 0, 0, 0);
        }
      }
    }
    __syncthreads();
  }
  // epilogue: per (32-token block, d): softmax over s of logits, weighted value sum
  int bidx = m0 >> 13;
  int len = lengths[bidx];
#pragma unroll
  for (int niv = 0; niv < 2; ++niv) {
    int d = (ny * 2 + wn) * 32 + niv * 16 + l15;   // global d in [0,512)
    int dloc = wn * 32 + niv * 16 + l15;           // wg-local d in [0,64)
    float bwv = bw[d], bvv = bv[d];
#pragma unroll
    for (int blk = 0; blk < 2; ++blk) {
      int growL = m0 + wm * 64 + blk * 32;
      int nb = (growL & 8191) >> 5;
      int vcnt = min(max(len - nb * 32, 0), 32);
      float lg[8], vl[8];
      float mx = FMIN_F;
#pragma unroll
      for (int j = 0; j < 8; ++j) {
        int mi = blk * 2 + (j >> 2);
        int r = j & 3;
        int s = ((j >> 2) << 4) + lg4 * 4 + r;
        float L = acc[mi][2 + niv][r] + bwv + pos_s[s * 64 + dloc];
        float V = acc[mi][niv][r] + bvv;
        lg[j] = L; vl[j] = V;
        if (s < vcnt) mx = fmaxf(mx, L);
      }
      mx = fmaxf(mx, __shfl_xor(mx, 16));
      mx = fmaxf(mx, __shfl_xor(mx, 32));
      float num = 0.f, den = 0.f;
#pragma unroll
      for (int j = 0; j < 8; ++j) {
        int s = ((j >> 2) << 4) + lg4 * 4 + (j & 3);
        if (s < vcnt) {
          float e = __expf(lg[j] - mx);
          num += e * vl[j];
          den += e;
        }
      }
      num += __shfl_xor(num, 16); num += __shfl_xor(num, 32);
      den += __shfl_xor(den, 16); den += __shfl_xor(den, 32);
      float o = (den > 0.f) ? (num / den) : 0.f;
      if (lg4 == 0)
        ctx[((size_t)bidx * 256 + nb) * 512 + d] = o;
    }
  }
}

// ---- fused: rmsnorm(ctx) -> bt  AND  keys = rmsnorm(bt @ idx_k_w + kb, kn) ----
__global__ __launch_bounds__(64) void k_btk(const float* __restrict__ ctx,
    const float* __restrict__ nw, const float* __restrict__ kw,
    const float* __restrict__ kb, const float* __restrict__ knw,
    float* __restrict__ bt, float* __restrict__ keys) {
  int row = blockIdx.x, lane = threadIdx.x;
  __shared__ float bs[512];
  const float* cp = ctx + (size_t)row * 512 + lane * 8;
  float x[8];
#pragma unroll
  for (int j = 0; j < 8; ++j) x[j] = cp[j];
  float ss = 0.f;
#pragma unroll
  for (int j = 0; j < 8; ++j) ss += x[j] * x[j];
#pragma unroll
  for (int o = 1; o < 64; o <<= 1) ss += __shfl_xor(ss, o);
  float sc = rsqrtf(ss * (1.f / 512.f) + 1e-6f);
  float* op = bt + (size_t)row * 512 + lane * 8;
  const float* nwp = nw + lane * 8;
#pragma unroll
  for (int j = 0; j < 8; ++j) {
    float y = x[j] * sc * nwp[j];
    op[j] = y;
    bs[lane * 8 + j] = y;
  }
  __syncthreads();
  float a = kb[lane];
  for (int k = 0; k < 512; ++k) a += bs[k] * kw[k * 64 + lane];
  float s2 = a * a;
#pragma unroll
  for (int o = 1; o < 64; o <<= 1) s2 += __shfl_xor(s2, o);
  keys[(size_t)row * 64 + lane] = a * rsqrtf(s2 * (1.f / 64.f) + 1e-6f) * knw[lane];
}

// ---- per-b: ql, qh, hw, scores, top-64 (keys staged in LDS, padded stride) ----
__global__ __launch_bounds__(256) void k_sel(
    const float* __restrict__ query, const float* __restrict__ keys,
    const int* __restrict__ lengths,
    const float* __restrict__ qdw, const float* __restrict__ qdb,
    const float* __restrict__ quw, const float* __restrict__ qub,
    const float* __restrict__ hww, const float* __restrict__ hwb,
    const float* __restrict__ qnw, int* __restrict__ idxs) {
  int b = blockIdx.x, tid = threadIdx.x;
  __shared__ float qs[512], qls[64], qhs[512], hws[8], scs[256];
  __shared__ float ks_s[256 * 65];        // padded: conflict-free
  int wave = tid >> 6, lane = tid & 63;
  {
    const float* kb_g = keys + (size_t)b * 256 * 64;
    for (int r = wave; r < 256; r += 4)
      ks_s[r * 65 + lane] = kb_g[r * 64 + lane];
  }
  for (int i = tid; i < 512; i += 256) qs[i] = query[b * 512 + i];
  __syncthreads();
  if (tid < 64) {
    float a = qdb[tid];
    for (int k = 0; k < 512; ++k) a += qs[k] * qdw[k * 64 + tid];
    float ss = a * a;
#pragma unroll
    for (int o = 1; o < 64; o <<= 1) ss += __shfl_xor(ss, o);
    qls[tid] = a * rsqrtf(ss * (1.f / 64.f) + 1e-6f) * qnw[tid];
  }
  __syncthreads();
  for (int j = tid; j < 512; j += 256) {
    float a = qub[j];
    for (int k = 0; k < 64; ++k) a += qls[k] * quw[k * 512 + j];
    qhs[j] = a;
  }
  if (tid < 8) {
    float a = hwb[tid];
    for (int k = 0; k < 512; ++k) a += qs[k] * hww[k * 8 + tid];
    hws[tid] = a;
  }
  __syncthreads();
  if (tid == 0) {
    float m = hws[0];
    for (int h = 1; h < 8; ++h) m = fmaxf(m, hws[h]);
    float s = 0.f, e[8];
    for (int h = 0; h < 8; ++h) { e[h] = __expf(hws[h] - m); s += e[h]; }
    for (int h = 0; h < 8; ++h) hws[h] = e[h] / s;
  }
  __syncthreads();
  {
    int len = lengths[b];
    int n = tid;
    float sc = FMIN_F;
    if (n * 32 < len) {
      sc = 0.f;
      const float* kr = ks_s + n * 65;
      for (int h = 0; h < 8; ++h) {
        float dp = 0.f;
#pragma unroll
        for (int i = 0; i < 64; ++i) dp += qhs[h * 64 + i] * kr[i];
        sc += fmaxf(dp, 0.f) * hws[h];
      }
    }
    scs[n] = sc;
  }
  __syncthreads();
  if (tid < 64) {
    unsigned long long kk[4];
#pragma unroll
    for (int j = 0; j < 4; ++j) {
      int n = j * 64 + tid;
      unsigned u = __float_as_uint(scs[n]);
      u = (u & 0x80000000u) ? ~u : (u | 0x80000000u);
      kk[j] = ((unsigned long long)u << 32) | (unsigned long long)(255 - n);
    }
    for (int r = 0; r < 64; ++r) {
      unsigned long long m = kk[0];
      if (kk[1] > m) m = kk[1];
      if (kk[2] > m) m = kk[2];
      if (kk[3] > m) m = kk[3];
#pragma unroll
      for (int o = 1; o < 64; o <<= 1) {
        unsigned long long t = __shfl_xor(m, o);
        if (t > m) m = t;
      }
      if (tid == 0) idxs[b * 64 + r] = 255 - (int)(m & 0xFFull);
#pragma unroll
      for (int j = 0; j < 4; ++j) if (kk[j] == m) kk[j] = 0ull;
    }
  }
}

// ---- assemble src rows (recent | sel | gtok) as bf16 + smask + zero pad rows --
__global__ __launch_bounds__(128) void k_src(const float* __restrict__ tok,
    const float* __restrict__ bt, const float* __restrict__ gsum,
    const int* __restrict__ lengths, const int* __restrict__ idxs,
    unsigned short* __restrict__ src_bf, int* __restrict__ smask) {
  int b = blockIdx.x, n = blockIdx.y, tid = threadIdx.x;
  int d0 = tid * 4;
  if (n >= 193) {   // zero a pad row (rows 1544..1663 of the 1664-row buffer)
    size_t prow = 1544 + (size_t)b * 15 + (n - 193);
    ushort4 z; z.x = 0; z.y = 0; z.z = 0; z.w = 0;
    *(ushort4*)(src_bf + prow * 512 + d0) = z;
    return;
  }
  int len = lengths[b];
  float v0 = 0.f, v1 = 0.f, v2 = 0.f, v3 = 0.f;
  int sm = 0;
  if (n < 128) {
    int cl = min(max(len, 0), 8192);
    int start = max(cl - 128, 0);
    int pos = min(start + n, 8191);
    bool vis = n < min(cl, 128);
    sm = vis ? 0 : 1;
    if (vis) {
      const float* tp = tok + ((size_t)b * 8192 + pos) * 512 + d0;
      float pn = (float)n;
#pragma unroll
      for (int j = 0; j < 4; ++j) {
        int d = d0 + j;
        int i = d >> 1;
        float ang = pn * __expf(-9.210340371976184f * ((float)i * (1.f / 256.f)));
        float pe = (d & 1) ? cosf(ang) : sinf(ang);
        float t = tp[j] + pe;
        if (j == 0) v0 = t; else if (j == 1) v1 = t; else if (j == 2) v2 = t; else v3 = t;
      }
    }
  } else if (n < 192) {
    int idx = idxs[b * 64 + (n - 128)];
    sm = (idx * 32 >= len) ? 1 : 0;
    const float* bp = bt + ((size_t)b * 256 + idx) * 512 + d0;
    v0 = bp[0]; v1 = bp[1]; v2 = bp[2]; v3 = bp[3];
  } else {
    sm = 0;
    float inv = 1.f / (float)max(len, 1);
    const float* gp = gsum + b * 512 + d0;
    v0 = gp[0] * inv; v1 = gp[1] * inv; v2 = gp[2] * inv; v3 = gp[3] * inv;
  }
  ushort4 o;
  o.x = rne_bf16(v0); o.y = rne_bf16(v1); o.z = rne_bf16(v2); o.w = rne_bf16(v3);
  *(ushort4*)(src_bf + ((size_t)b * 193 + n) * 512 + d0) = o;
  if (tid == 0) smask[b * 193 + n] = sm;
}

// ---- pooling k/v GEMM (bf16 MFMA): kv[r][0:512]=src@Wk, [512:1024]=src@Wv -----
__global__ __launch_bounds__(256) void k_kvm(
    const unsigned short* __restrict__ src_bf, const unsigned short* __restrict__ PW,
    float* __restrict__ kv) {
  __shared__ __align__(16) unsigned short As[128 * 64];
  __shared__ __align__(16) unsigned short Bs[128 * 64];
  int m0 = blockIdx.x << 7, n0 = blockIdx.y << 7;
  int tid = threadIdx.x;
  int wave = tid >> 6, lane = tid & 63;
  int wm = wave >> 1, wn = wave & 1;
  int l15 = lane & 15, lg4 = lane >> 4;
  int lrow = lane >> 3, lcol = lane & 7;
  f32x4 acc[4][4];
#pragma unroll
  for (int i = 0; i < 4; ++i)
#pragma unroll
    for (int j = 0; j < 4; ++j) acc[i][j] = (f32x4){0.f, 0.f, 0.f, 0.f};
  for (int kk = 0; kk < 8; ++kk) {
    int k0 = kk << 6;
#pragma unroll
    for (int j = 0; j < 4; ++j) {
      int r = wave * 32 + j * 8 + lrow;
      glds16(src_bf + (size_t)(m0 + r) * 512 + k0 + lcol * 8, As + r * 64 + lcol * 8);
      glds16(PW + (size_t)(n0 + r) * 512 + k0 + lcol * 8, Bs + r * 64 + lcol * 8);
    }
    __syncthreads();
#pragma unroll
    for (int ks = 0; ks < 2; ++ks) {
      int kb = ks * 32 + lg4 * 8;
      short8 av[4], bf[4];
#pragma unroll
      for (int i = 0; i < 4; ++i) {
        av[i] = *(const short8*)(As + (wm * 64 + i * 16 + l15) * 64 + kb);
        bf[i] = *(const short8*)(Bs + (wn * 64 + i * 16 + l15) * 64 + kb);
      }
#pragma unroll
      for (int mi = 0; mi < 4; ++mi)
#pragma unroll
        for (int ni = 0; ni < 4; ++ni)
          acc[mi][ni] = __builtin_amdgcn_mfma_f32_16x16x32_bf16(av[mi], bf[ni], acc[mi][ni], 0, 0, 0);
    }
    __syncthreads();
  }
#pragma unroll
  for (int mi = 0; mi < 4; ++mi)
#pragma unroll
    for (int ni = 0; ni < 4; ++ni)
#pragma unroll
      for (int rr = 0; rr < 4; ++rr) {
        int grow = m0 + wm * 64 + mi * 16 + lg4 * 4 + rr;
        kv[(size_t)grow * 1024 + n0 + wn * 64 + ni * 16 + l15] = acc[mi][ni][rr];
      }
}

// ---- qproj = query @ pool_q_w + pool_q_b (direct) -----------------------------
__global__ __launch_bounds__(256) void k_qproj(const float* __restrict__ query,
    const float* __restrict__ pqw, const float* __restrict__ pqb,
    float* __restrict__ qp) {
  int b = blockIdx.x;
  int c = blockIdx.y * 256 + threadIdx.x;
  __shared__ float qs[512];
  for (int i = threadIdx.x; i < 512; i += 256) qs[i] = query[b * 512 + i];
  __syncthreads();
  float a = pqb[c];
  for (int k = 0; k < 512; ++k) a += qs[k] * pqw[(size_t)k * 512 + c];
  qp[b * 512 + c] = a;
}

// ---- latent cross-attention + rmsnorm -> out (coalesced, branchless PV) -------
__global__ __launch_bounds__(256) void k_attn(const float* __restrict__ kv,
    const float* __restrict__ qproj, const float* __restrict__ latents,
    const float* __restrict__ pkb, const float* __restrict__ pvb,
    const float* __restrict__ pnw, const int* __restrict__ smask,
    float* __restrict__ out) {
  int b = blockIdx.x, l = blockIdx.y, tid = threadIdx.x;
  int wave = tid >> 6, lane = tid & 63;
  __shared__ float lq_s[512];
  __shared__ float w_s[256];
  __shared__ float red_s[256];
  __shared__ int sm_s[256];
  for (int i = tid; i < 512; i += 256) lq_s[i] = latents[l * 512 + i] + qproj[b * 512 + i];
  sm_s[tid] = (tid < 193) ? smask[b * 193 + tid] : 1;
  w_s[tid] = FMIN_F;
  __syncthreads();
  red_s[tid] = (tid < 193 && sm_s[tid]) ? 1.f : 0.f;
  __syncthreads();
  for (int s = 128; s > 0; s >>= 1) { if (tid < s) red_s[tid] += red_s[tid + s]; __syncthreads(); }
  bool allm = (red_s[0] > 192.5f);
  __syncthreads();
  red_s[tid] = pkb[tid] * lq_s[tid] + pkb[tid + 256] * lq_s[tid + 256];
  __syncthreads();
  for (int s = 128; s > 0; s >>= 1) { if (tid < s) red_s[tid] += red_s[tid + s]; __syncthreads(); }
  float pkbdot = red_s[0];
  __syncthreads();
  for (int n = wave; n < 193; n += 4) {
    const float* kr = kv + ((size_t)b * 193 + n) * 1024 + lane * 8;
    float4 a = *(const float4*)(kr);
    float4 c = *(const float4*)(kr + 4);
    const float* lq = lq_s + lane * 8;
    float dp = a.x * lq[0] + a.y * lq[1] + a.z * lq[2] + a.w * lq[3]
             + c.x * lq[4] + c.y * lq[5] + c.z * lq[6] + c.w * lq[7];
#pragma unroll
    for (int o = 1; o < 64; o <<= 1) dp += __shfl_xor(dp, o);
    if (lane == 0) {
      float sc = (dp + pkbdot) * 0.04419417382415922f;
      if (sm_s[n] && !allm) sc = FMIN_F;
      w_s[n] = sc;
    }
  }
  __syncthreads();
  float sc = w_s[tid];
  red_s[tid] = sc;
  __syncthreads();
  for (int s = 128; s > 0; s >>= 1) { if (tid < s) red_s[tid] = fmaxf(red_s[tid], red_s[tid + s]); __syncthreads(); }
  float mx = red_s[0];
  __syncthreads();
  float e = __expf(sc - mx);
  w_s[tid] = e;
  red_s[tid] = e;
  __syncthreads();
  for (int s = 128; s > 0; s >>= 1) { if (tid < s) red_s[tid] += red_s[tid + s]; __syncthreads(); }
  float invS = 1.f / red_s[0];
  __syncthreads();
  float o0 = 0.f, o1 = 0.f;
  const float* vbase = kv + (size_t)b * 193 * 1024 + 512;
#pragma unroll 4
  for (int n = 0; n < 193; ++n) {
    float w = w_s[n];
    const float* vr = vbase + (size_t)n * 1024;
    o0 += w * vr[tid];
    o1 += w * vr[tid + 256];
  }
  o0 = o0 * invS + pvb[tid];
  o1 = o1 * invS + pvb[tid + 256];
  red_s[tid] = o0 * o0 + o1 * o1;
  __syncthreads();
  for (int s = 128; s > 0; s >>= 1) { if (tid < s) red_s[tid] += red_s[tid + s]; __syncthreads(); }
  float scale = rsqrtf(red_s[0] * (1.f / 512.f) + 1e-6f);
  if (allm) scale = 0.f;
  out[((size_t)b * 16 + l) * 512 + tid] = o0 * scale * pnw[tid];
  out[((size_t)b * 16 + l) * 512 + tid + 256] = o1 * scale * pnw[tid + 256];
}

extern "C" void kernel_launch(void* const* d_in, const int* in_sizes, int n_in,
                              void* d_out, int out_size, void* d_ws, size_t ws_size,
                              hipStream_t stream) {
  (void)in_sizes; (void)n_in; (void)out_size; (void)ws_size;
  const float* tokens      = (const float*)d_in[0];
  const int*   lengths     = (const int*)d_in[1];
  const float* query       = (const float*)d_in[2];
  const float* comp_wv     = (const float*)d_in[3];
  const float* comp_bv     = (const float*)d_in[4];
  const float* comp_ww     = (const float*)d_in[5];
  const float* comp_bw     = (const float*)d_in[6];
  const float* comp_pos    = (const float*)d_in[7];
  const float* comp_norm_w = (const float*)d_in[8];
  const float* idx_qd_w    = (const float*)d_in[9];
  const float* idx_qd_b    = (const float*)d_in[10];
  const float* idx_qu_w    = (const float*)d_in[11];
  const float* idx_qu_b    = (const float*)d_in[12];
  const float* idx_k_w     = (const float*)d_in[13];
  const float* idx_k_b     = (const float*)d_in[14];
  const float* idx_hw_w    = (const float*)d_in[15];
  const float* idx_hw_b    = (const float*)d_in[16];
  const float* idx_qn_w    = (const float*)d_in[17];
  const float* idx_kn_w    = (const float*)d_in[18];
  const float* pool_latents= (const float*)d_in[19];
  const float* pool_q_w    = (const float*)d_in[20];
  const float* pool_q_b    = (const float*)d_in[21];
  const float* pool_k_w    = (const float*)d_in[22];
  const float* pool_k_b    = (const float*)d_in[23];
  const float* pool_v_w    = (const float*)d_in[24];
  const float* pool_v_b    = (const float*)d_in[25];
  const float* pool_norm_w = (const float*)d_in[26];

  char* ws = (char*)d_ws;
  unsigned short* A2    = (unsigned short*)(ws + 0);           // 128 MB [0, 134217728)
  float*          bt    = (float*)(ws + 0);                    // 4 MB   (alias, post-GEMM)
  float*          keys  = (float*)(ws + 4194304);              // 512 KB (alias)
  int*            idxs  = (int*)  (ws + 4718592);              // 2 KB   (alias)
  int*            smask = (int*)  (ws + 4720640);              // 8 KB   (alias)
  float*          qproj = (float*)(ws + 4728832);              // 16 KB  (alias)
  unsigned short* PW2   = (unsigned short*)(ws + 4745216);     // 1 MB   (alias)
  unsigned short* src_bf= (unsigned short*)(ws + 5793792);     // 1.7 MB (alias, 1664 rows)
  float*          kv    = (float*)(ws + 7497728);              // 6.8 MB (alias, 1664 rows)
  float*          gpart = (float*)(ws + 134217728);            // 8 MB
  float*          ctx   = (float*)(ws + 142606336);            // 4 MB
  unsigned short* W2    = (unsigned short*)(ws + 146800640);   // 2 MB
  float*          gsum  = (float*)(ws + 148897792);            // 16 KB

  k_wsplit<<<dim3(8, 8, 2), 256, 0, stream>>>(comp_wv, comp_ww, W2);
  k_split<<<4096, 256, 0, stream>>>(tokens, lengths, A2, gpart);
  k_gemm128<<<dim3(8, 512), 256, 0, stream>>>(A2, W2, comp_bv, comp_bw,
                                              comp_pos, lengths, ctx);
  k_gred<<<dim3(8, 2), 256, 0, stream>>>(gpart, gsum);
  // A2 region free from here on
  k_wpool<<<dim3(8, 8, 2), 256, 0, stream>>>(pool_k_w, pool_v_w, PW2);
  k_btk<<<2048, 64, 0, stream>>>(ctx, comp_norm_w, idx_k_w, idx_k_b, idx_kn_w,
                                 bt, keys);
  k_sel<<<8, 256, 0, stream>>>(query, keys, lengths, idx_qd_w, idx_qd_b,
                               idx_qu_w, idx_qu_b, idx_hw_w, idx_hw_b,
                               idx_qn_w, idxs);
  k_src<<<dim3(8, 208), 128, 0, stream>>>(tokens, bt, gsum, lengths, idxs,
                                          src_bf, smask);
  k_kvm<<<dim3(13, 8), 256, 0, stream>>>(src_bf, PW2, kv);
  k_qproj<<<dim3(8, 2), 256, 0, stream>>>(query, pool_q_w, pool_q_b, qproj);
  k_attn<<<dim3(8, 16), 256, 0, stream>>>(kv, qproj, pool_latents, pool_k_b,
                                          pool_v_b, pool_norm_w, smask,
                                          (float*)d_out);
}

// Round 15
// 402.409 us; speedup vs baseline: 1.1320x; 1.0561x over previous
//
#include <hip/hip_runtime.h>
#include <stdint.h>

typedef __attribute__((ext_vector_type(8))) _Float16 half8;
typedef __attribute__((ext_vector_type(8))) short short8;
typedef __attribute__((ext_vector_type(4))) float f32x4;

#define FMIN_F (-3.4028234663852886e38f)

__device__ __forceinline__ unsigned short rne_bf16(float x) {
  unsigned u = __float_as_uint(x);
  unsigned r = (u + 0x7FFFu + ((u >> 16) & 1u)) >> 16;
  return (unsigned short)r;
}

__device__ __forceinline__ void split16(float x, unsigned short& h, unsigned short& l) {
  _Float16 hh = (_Float16)x;
  float r = x - (float)hh;
  _Float16 ll = (_Float16)r;
  union { _Float16 f; unsigned short u; } a, b;
  a.f = hh; b.f = ll;
  h = a.u; l = b.u;
}

__device__ __forceinline__ void glds16(const unsigned short* g, unsigned short* l) {
  __builtin_amdgcn_global_load_lds(
      (const __attribute__((address_space(1))) unsigned int*)g,
      (__attribute__((address_space(3))) unsigned int*)l, 16, 0, 0);
}

// ---- tokens f32 -> A2=[Ah|Al] rows + per-block partial column sums (NO atomics)
__global__ __launch_bounds__(256) void k_split(const float* __restrict__ tok,
    const int* __restrict__ lengths, unsigned short* __restrict__ A2,
    float* __restrict__ gpart) {
  __shared__ float ps[512];
  int wg = blockIdx.x, tid = threadIdx.x;
  int colv = tid & 127;
  int rh = tid >> 7;
  int r0 = wg << 4;
  int b0 = r0 >> 13;
  int part = wg & 511;
  int len = lengths[b0];
  float sx = 0.f, sy = 0.f, sz = 0.f, sw = 0.f;
#pragma unroll
  for (int i = 0; i < 8; ++i) {
    int row = r0 + (i << 1) + rh;
    const float4 v = ((const float4*)(tok + (size_t)row * 512))[colv];
    ushort4 oh, ol;
    split16(v.x, oh.x, ol.x); split16(v.y, oh.y, ol.y);
    split16(v.z, oh.z, ol.z); split16(v.w, oh.w, ol.w);
    *(ushort4*)(A2 + (size_t)row * 1024 + colv * 4) = oh;
    *(ushort4*)(A2 + (size_t)row * 1024 + 512 + colv * 4) = ol;
    if ((row & 8191) < len) { sx += v.x; sy += v.y; sz += v.z; sw += v.w; }
  }
  if (rh == 0) {
    ps[colv * 4 + 0] = sx; ps[colv * 4 + 1] = sy;
    ps[colv * 4 + 2] = sz; ps[colv * 4 + 3] = sw;
  }
  __syncthreads();
  if (rh == 1) {
    ps[colv * 4 + 0] += sx; ps[colv * 4 + 1] += sy;
    ps[colv * 4 + 2] += sz; ps[colv * 4 + 3] += sw;
  }
  __syncthreads();
  float* gp = gpart + ((size_t)b0 * 512 + part) * 512;
  gp[tid] = ps[tid];
  gp[tid + 256] = ps[tid + 256];
}

// ---- fused weight packing: z<2 -> comp W2 split-f16 ; z>=2 -> pool PW bf16 ----
__global__ __launch_bounds__(256) void k_wpack4(const float* __restrict__ wv,
    const float* __restrict__ ww, const float* __restrict__ pwk,
    const float* __restrict__ pwv, unsigned short* __restrict__ W2,
    unsigned short* __restrict__ PW) {
  __shared__ float t[64][65];
  int kk0 = blockIdx.x * 64, d0 = blockIdx.y * 64, z = blockIdx.z;
  int tid = threadIdx.x;
  const float* W = (z == 0) ? wv : (z == 1) ? ww : (z == 2) ? pwk : pwv;
  for (int i = tid; i < 4096; i += 256) {
    int k = i >> 6, d = i & 63;
    t[k][d] = W[(size_t)(kk0 + k) * 512 + d0 + d];
  }
  __syncthreads();
  int dr = tid >> 2, kq = tid & 3;
  if (z < 2) {
    int m = z;
    int d = d0 + dr;
    int n = (d >> 5) * 64 + m * 32 + (d & 31);
    size_t baseH = (size_t)n * 1024 + kk0 + kq * 16;
    for (int q = 0; q < 16; ++q) {
      unsigned short hh, ll;
      split16(t[kq * 16 + q][dr], hh, ll);
      W2[baseH + q] = hh;
      W2[baseH + 512 + q] = ll;
    }
  } else {
    int m = z - 2;
    int n = m * 512 + d0 + dr;
    size_t base = (size_t)n * 512 + kk0 + kq * 16;
    for (int q = 0; q < 16; ++q)
      PW[base + q] = rne_bf16(t[kq * 16 + q][dr]);
  }
}

// ---- 128x128-tile split-f16 GEMM + XOR-swizzled LDS + XCD-local A-panels ------
__global__ __launch_bounds__(256) void k_gemm128(
    const unsigned short* __restrict__ A2, const unsigned short* __restrict__ W2,
    const float* __restrict__ bv, const float* __restrict__ bw,
    const float* __restrict__ cpos, const int* __restrict__ lengths,
    float* __restrict__ ctx) {
  __shared__ __align__(16) unsigned short Ash[128 * 64];
  __shared__ __align__(16) unsigned short Asl[128 * 64];
  __shared__ __align__(16) unsigned short Bsh[128 * 64];
  __shared__ __align__(16) unsigned short Bsl[128 * 64];
  __shared__ float pos_s[32 * 64];
  int ny = blockIdx.y & 7;
  int mt = blockIdx.x * 64 + (blockIdx.y >> 3);
  int tid = threadIdx.x;
  int wave = tid >> 6, lane = tid & 63;
  int m0 = mt << 7, n0 = ny << 7;
  for (int i = tid; i < 2048; i += 256) {
    int s = i >> 6, c = i & 63;
    pos_s[i] = cpos[s * 512 + ny * 64 + c];
  }
  f32x4 acc[4][4];
#pragma unroll
  for (int i = 0; i < 4; ++i)
#pragma unroll
    for (int j = 0; j < 4; ++j) acc[i][j] = (f32x4){0.f, 0.f, 0.f, 0.f};
  int lrow = lane >> 3, lcol = lane & 7;
  int wm = wave >> 1, wn = wave & 1;
  int l15 = lane & 15, lg4 = lane >> 4;
  int scs_ = (lcol ^ lrow) * 8;
  int rx = (l15 & 7);
  for (int kk = 0; kk < 8; ++kk) {
    int k0 = kk << 6;
#pragma unroll
    for (int j = 0; j < 4; ++j) {
      int r = wave * 32 + j * 8 + lrow;
      size_t ga = (size_t)(m0 + r) * 1024 + k0 + scs_;
      size_t gb = (size_t)(n0 + r) * 1024 + k0 + scs_;
      int ls = r * 64 + lcol * 8;
      glds16(A2 + ga, Ash + ls);
      glds16(A2 + ga + 512, Asl + ls);
      glds16(W2 + gb, Bsh + ls);
      glds16(W2 + gb + 512, Bsl + ls);
    }
    __syncthreads();
#pragma unroll
    for (int ks = 0; ks < 2; ++ks) {
      int cofs = ((ks * 4 + lg4) ^ rx) * 8;
      half8 bh[4], bl[4];
#pragma unroll
      for (int i = 0; i < 4; ++i) {
        bh[i] = *(const half8*)(Bsh + (wn * 64 + i * 16 + l15) * 64 + cofs);
        bl[i] = *(const half8*)(Bsl + (wn * 64 + i * 16 + l15) * 64 + cofs);
      }
#pragma unroll
      for (int mi = 0; mi < 4; ++mi) {
        half8 ah = *(const half8*)(Ash + (wm * 64 + mi * 16 + l15) * 64 + cofs);
        half8 al = *(const half8*)(Asl + (wm * 64 + mi * 16 + l15) * 64 + cofs);
#pragma unroll
        for (int ni = 0; ni < 4; ++ni) {
          acc[mi][ni] = __builtin_amdgcn_mfma_f32_16x16x32_f16(ah, bh[ni], acc[mi][ni], 0, 0, 0);
          acc[mi][ni] = __builtin_amdgcn_mfma_f32_16x16x32_f16(al, bh[ni], acc[mi][ni], 0, 0, 0);
          acc[mi][ni] = __builtin_amdgcn_mfma_f32_16x16x32_f16(ah, bl[ni], acc[mi][ni], 0, 0, 0);
        }
      }
    }
    __syncthreads();
  }
  int bidx = m0 >> 13;
  int len = lengths[bidx];
#pragma unroll
  for (int niv = 0; niv < 2; ++niv) {
    int d = (ny * 2 + wn) * 32 + niv * 16 + l15;
    int dloc = wn * 32 + niv * 16 + l15;
    float bwv = bw[d], bvv = bv[d];
#pragma unroll
    for (int blk = 0; blk < 2; ++blk) {
      int growL = m0 + wm * 64 + blk * 32;
      int nb = (growL & 8191) >> 5;
      int vcnt = min(max(len - nb * 32, 0), 32);
      float lg[8], vl[8];
      float mx = FMIN_F;
#pragma unroll
      for (int j = 0; j < 8; ++j) {
        int mi = blk * 2 + (j >> 2);
        int r = j & 3;
        int s = ((j >> 2) << 4) + lg4 * 4 + r;
        float L = acc[mi][2 + niv][r] + bwv + pos_s[s * 64 + dloc];
        float V = acc[mi][niv][r] + bvv;
        lg[j] = L; vl[j] = V;
        if (s < vcnt) mx = fmaxf(mx, L);
      }
      mx = fmaxf(mx, __shfl_xor(mx, 16));
      mx = fmaxf(mx, __shfl_xor(mx, 32));
      float num = 0.f, den = 0.f;
#pragma unroll
      for (int j = 0; j < 8; ++j) {
        int s = ((j >> 2) << 4) + lg4 * 4 + (j & 3);
        if (s < vcnt) {
          float e = __expf(lg[j] - mx);
          num += e * vl[j];
          den += e;
        }
      }
      num += __shfl_xor(num, 16); num += __shfl_xor(num, 32);
      den += __shfl_xor(den, 16); den += __shfl_xor(den, 32);
      float o = (den > 0.f) ? (num / den) : 0.f;
      if (lg4 == 0)
        ctx[((size_t)bidx * 256 + nb) * 512 + d] = o;
    }
  }
}

// ---- fused tiny: bid<16 -> gsum reduce ; bid>=16 -> qproj ---------------------
__global__ __launch_bounds__(256) void k_gq(const float* __restrict__ gpart,
    float* __restrict__ gsum, const float* __restrict__ query,
    const float* __restrict__ pqw, const float* __restrict__ pqb,
    float* __restrict__ qp) {
  __shared__ float qs[512];
  int bid = blockIdx.x, tid = threadIdx.x;
  if (bid < 16) {
    int b = bid >> 1, half = bid & 1;
    int c = half * 256 + tid;
    float a0 = 0.f;
    for (int part = 0; part < 512; ++part)
      a0 += gpart[((size_t)b * 512 + part) * 512 + c];
    gsum[b * 512 + c] = a0;
  } else {
    int b = (bid - 16) >> 1;
    int c = ((bid - 16) & 1) * 256 + tid;
    for (int i = tid; i < 512; i += 256) qs[i] = query[b * 512 + i];
    __syncthreads();
    float a = pqb[c];
    for (int k = 0; k < 512; ++k) a += qs[k] * pqw[(size_t)k * 512 + c];
    qp[b * 512 + c] = a;
  }
}

// ---- fused: rmsnorm(ctx) -> bt  AND  keys = rmsnorm(bt @ idx_k_w + kb, kn) ----
__global__ __launch_bounds__(64) void k_btk(const float* __restrict__ ctx,
    const float* __restrict__ nw, const float* __restrict__ kw,
    const float* __restrict__ kb, const float* __restrict__ knw,
    float* __restrict__ bt, float* __restrict__ keys) {
  int row = blockIdx.x, lane = threadIdx.x;
  __shared__ float bs[512];
  const float* cp = ctx + (size_t)row * 512 + lane * 8;
  float x[8];
#pragma unroll
  for (int j = 0; j < 8; ++j) x[j] = cp[j];
  float ss = 0.f;
#pragma unroll
  for (int j = 0; j < 8; ++j) ss += x[j] * x[j];
#pragma unroll
  for (int o = 1; o < 64; o <<= 1) ss += __shfl_xor(ss, o);
  float sc = rsqrtf(ss * (1.f / 512.f) + 1e-6f);
  float* op = bt + (size_t)row * 512 + lane * 8;
  const float* nwp = nw + lane * 8;
#pragma unroll
  for (int j = 0; j < 8; ++j) {
    float y = x[j] * sc * nwp[j];
    op[j] = y;
    bs[lane * 8 + j] = y;
  }
  __syncthreads();
  float a = kb[lane];
  for (int k = 0; k < 512; ++k) a += bs[k] * kw[k * 64 + lane];
  float s2 = a * a;
#pragma unroll
  for (int o = 1; o < 64; o <<= 1) s2 += __shfl_xor(s2, o);
  keys[(size_t)row * 64 + lane] = a * rsqrtf(s2 * (1.f / 64.f) + 1e-6f) * knw[lane];
}

// ---- per-b: ql, qh, hw, scores, top-64 ----------------------------------------
__global__ __launch_bounds__(256) void k_sel(
    const float* __restrict__ query, const float* __restrict__ keys,
    const int* __restrict__ lengths,
    const float* __restrict__ qdw, const float* __restrict__ qdb,
    const float* __restrict__ quw, const float* __restrict__ qub,
    const float* __restrict__ hww, const float* __restrict__ hwb,
    const float* __restrict__ qnw, int* __restrict__ idxs) {
  int b = blockIdx.x, tid = threadIdx.x;
  __shared__ float qs[512], qls[64], qhs[512], hws[8], scs[256];
  __shared__ float ks_s[256 * 65];
  int wave = tid >> 6, lane = tid & 63;
  {
    const float* kb_g = keys + (size_t)b * 256 * 64;
    for (int r = wave; r < 256; r += 4)
      ks_s[r * 65 + lane] = kb_g[r * 64 + lane];
  }
  for (int i = tid; i < 512; i += 256) qs[i] = query[b * 512 + i];
  __syncthreads();
  if (tid < 64) {
    float a = qdb[tid];
    for (int k = 0; k < 512; ++k) a += qs[k] * qdw[k * 64 + tid];
    float ss = a * a;
#pragma unroll
    for (int o = 1; o < 64; o <<= 1) ss += __shfl_xor(ss, o);
    qls[tid] = a * rsqrtf(ss * (1.f / 64.f) + 1e-6f) * qnw[tid];
  }
  __syncthreads();
  for (int j = tid; j < 512; j += 256) {
    float a = qub[j];
    for (int k = 0; k < 64; ++k) a += qls[k] * quw[k * 512 + j];
    qhs[j] = a;
  }
  if (tid < 8) {
    float a = hwb[tid];
    for (int k = 0; k < 512; ++k) a += qs[k] * hww[k * 8 + tid];
    hws[tid] = a;
  }
  __syncthreads();
  if (tid == 0) {
    float m = hws[0];
    for (int h = 1; h < 8; ++h) m = fmaxf(m, hws[h]);
    float s = 0.f, e[8];
    for (int h = 0; h < 8; ++h) { e[h] = __expf(hws[h] - m); s += e[h]; }
    for (int h = 0; h < 8; ++h) hws[h] = e[h] / s;
  }
  __syncthreads();
  {
    int len = lengths[b];
    int n = tid;
    float sc = FMIN_F;
    if (n * 32 < len) {
      sc = 0.f;
      const float* kr = ks_s + n * 65;
      for (int h = 0; h < 8; ++h) {
        float dp = 0.f;
#pragma unroll
        for (int i = 0; i < 64; ++i) dp += qhs[h * 64 + i] * kr[i];
        sc += fmaxf(dp, 0.f) * hws[h];
      }
    }
    scs[n] = sc;
  }
  __syncthreads();
  if (tid < 64) {
    unsigned long long kk[4];
#pragma unroll
    for (int j = 0; j < 4; ++j) {
      int n = j * 64 + tid;
      unsigned u = __float_as_uint(scs[n]);
      u = (u & 0x80000000u) ? ~u : (u | 0x80000000u);
      kk[j] = ((unsigned long long)u << 32) | (unsigned long long)(255 - n);
    }
    for (int r = 0; r < 64; ++r) {
      unsigned long long m = kk[0];
      if (kk[1] > m) m = kk[1];
      if (kk[2] > m) m = kk[2];
      if (kk[3] > m) m = kk[3];
#pragma unroll
      for (int o = 1; o < 64; o <<= 1) {
        unsigned long long t = __shfl_xor(m, o);
        if (t > m) m = t;
      }
      if (tid == 0) idxs[b * 64 + r] = 255 - (int)(m & 0xFFull);
#pragma unroll
      for (int j = 0; j < 4; ++j) if (kk[j] == m) kk[j] = 0ull;
    }
  }
}

// ---- assemble src rows (recent | sel | gtok) as bf16 + smask + zero pad rows --
__global__ __launch_bounds__(128) void k_src(const float* __restrict__ tok,
    const float* __restrict__ bt, const float* __restrict__ gsum,
    const int* __restrict__ lengths, const int* __restrict__ idxs,
    unsigned short* __restrict__ src_bf, int* __restrict__ smask) {
  int b = blockIdx.x, n = blockIdx.y, tid = threadIdx.x;
  int d0 = tid * 4;
  if (n >= 193) {
    size_t prow = 1544 + (size_t)b * 15 + (n - 193);
    ushort4 z; z.x = 0; z.y = 0; z.z = 0; z.w = 0;
    *(ushort4*)(src_bf + prow * 512 + d0) = z;
    return;
  }
  int len = lengths[b];
  float v0 = 0.f, v1 = 0.f, v2 = 0.f, v3 = 0.f;
  int sm = 0;
  if (n < 128) {
    int cl = min(max(len, 0), 8192);
    int start = max(cl - 128, 0);
    int pos = min(start + n, 8191);
    bool vis = n < min(cl, 128);
    sm = vis ? 0 : 1;
    if (vis) {
      const float* tp = tok + ((size_t)b * 8192 + pos) * 512 + d0;
      float pn = (float)n;
#pragma unroll
      for (int j = 0; j < 4; ++j) {
        int d = d0 + j;
        int i = d >> 1;
        float ang = pn * __expf(-9.210340371976184f * ((float)i * (1.f / 256.f)));
        float pe = (d & 1) ? cosf(ang) : sinf(ang);
        float t = tp[j] + pe;
        if (j == 0) v0 = t; else if (j == 1) v1 = t; else if (j == 2) v2 = t; else v3 = t;
      }
    }
  } else if (n < 192) {
    int idx = idxs[b * 64 + (n - 128)];
    sm = (idx * 32 >= len) ? 1 : 0;
    const float* bp = bt + ((size_t)b * 256 + idx) * 512 + d0;
    v0 = bp[0]; v1 = bp[1]; v2 = bp[2]; v3 = bp[3];
  } else {
    sm = 0;
    float inv = 1.f / (float)max(len, 1);
    const float* gp = gsum + b * 512 + d0;
    v0 = gp[0] * inv; v1 = gp[1] * inv; v2 = gp[2] * inv; v3 = gp[3] * inv;
  }
  ushort4 o;
  o.x = rne_bf16(v0); o.y = rne_bf16(v1); o.z = rne_bf16(v2); o.w = rne_bf16(v3);
  *(ushort4*)(src_bf + ((size_t)b * 193 + n) * 512 + d0) = o;
  if (tid == 0) smask[b * 193 + n] = sm;
}

// ---- pooling k/v GEMM (bf16 MFMA) ---------------------------------------------
__global__ __launch_bounds__(256) void k_kvm(
    const unsigned short* __restrict__ src_bf, const unsigned short* __restrict__ PW,
    float* __restrict__ kv) {
  __shared__ __align__(16) unsigned short As[128 * 64];
  __shared__ __align__(16) unsigned short Bs[128 * 64];
  int m0 = blockIdx.x << 7, n0 = blockIdx.y << 7;
  int tid = threadIdx.x;
  int wave = tid >> 6, lane = tid & 63;
  int wm = wave >> 1, wn = wave & 1;
  int l15 = lane & 15, lg4 = lane >> 4;
  int lrow = lane >> 3, lcol = lane & 7;
  f32x4 acc[4][4];
#pragma unroll
  for (int i = 0; i < 4; ++i)
#pragma unroll
    for (int j = 0; j < 4; ++j) acc[i][j] = (f32x4){0.f, 0.f, 0.f, 0.f};
  for (int kk = 0; kk < 8; ++kk) {
    int k0 = kk << 6;
#pragma unroll
    for (int j = 0; j < 4; ++j) {
      int r = wave * 32 + j * 8 + lrow;
      glds16(src_bf + (size_t)(m0 + r) * 512 + k0 + lcol * 8, As + r * 64 + lcol * 8);
      glds16(PW + (size_t)(n0 + r) * 512 + k0 + lcol * 8, Bs + r * 64 + lcol * 8);
    }
    __syncthreads();
#pragma unroll
    for (int ks = 0; ks < 2; ++ks) {
      int kb = ks * 32 + lg4 * 8;
      short8 av[4], bf[4];
#pragma unroll
      for (int i = 0; i < 4; ++i) {
        av[i] = *(const short8*)(As + (wm * 64 + i * 16 + l15) * 64 + kb);
        bf[i] = *(const short8*)(Bs + (wn * 64 + i * 16 + l15) * 64 + kb);
      }
#pragma unroll
      for (int mi = 0; mi < 4; ++mi)
#pragma unroll
        for (int ni = 0; ni < 4; ++ni)
          acc[mi][ni] = __builtin_amdgcn_mfma_f32_16x16x32_bf16(av[mi], bf[ni], acc[mi][ni], 0, 0, 0);
    }
    __syncthreads();
  }
#pragma unroll
  for (int mi = 0; mi < 4; ++mi)
#pragma unroll
    for (int ni = 0; ni < 4; ++ni)
#pragma unroll
      for (int rr = 0; rr < 4; ++rr) {
        int grow = m0 + wm * 64 + mi * 16 + lg4 * 4 + rr;
        kv[(size_t)grow * 1024 + n0 + wn * 64 + ni * 16 + l15] = acc[mi][ni][rr];
      }
}

// ---- latent cross-attention + rmsnorm -> out ----------------------------------
__global__ __launch_bounds__(256) void k_attn(const float* __restrict__ kv,
    const float* __restrict__ qproj, const float* __restrict__ latents,
    const float* __restrict__ pkb, const float* __restrict__ pvb,
    const float* __restrict__ pnw, const int* __restrict__ smask,
    float* __restrict__ out) {
  int b = blockIdx.x, l = blockIdx.y, tid = threadIdx.x;
  int wave = tid >> 6, lane = tid & 63;
  __shared__ float lq_s[512];
  __shared__ float w_s[256];
  __shared__ float red_s[256];
  __shared__ int sm_s[256];
  for (int i = tid; i < 512; i += 256) lq_s[i] = latents[l * 512 + i] + qproj[b * 512 + i];
  sm_s[tid] = (tid < 193) ? smask[b * 193 + tid] : 1;
  w_s[tid] = FMIN_F;
  __syncthreads();
  red_s[tid] = (tid < 193 && sm_s[tid]) ? 1.f : 0.f;
  __syncthreads();
  for (int s = 128; s > 0; s >>= 1) { if (tid < s) red_s[tid] += red_s[tid + s]; __syncthreads(); }
  bool allm = (red_s[0] > 192.5f);
  __syncthreads();
  red_s[tid] = pkb[tid] * lq_s[tid] + pkb[tid + 256] * lq_s[tid + 256];
  __syncthreads();
  for (int s = 128; s > 0; s >>= 1) { if (tid < s) red_s[tid] += red_s[tid + s]; __syncthreads(); }
  float pkbdot = red_s[0];
  __syncthreads();
  for (int n = wave; n < 193; n += 4) {
    const float* kr = kv + ((size_t)b * 193 + n) * 1024 + lane * 8;
    float4 a = *(const float4*)(kr);
    float4 c = *(const float4*)(kr + 4);
    const float* lq = lq_s + lane * 8;
    float dp = a.x * lq[0] + a.y * lq[1] + a.z * lq[2] + a.w * lq[3]
             + c.x * lq[4] + c.y * lq[5] + c.z * lq[6] + c.w * lq[7];
#pragma unroll
    for (int o = 1; o < 64; o <<= 1) dp += __shfl_xor(dp, o);
    if (lane == 0) {
      float sc = (dp + pkbdot) * 0.04419417382415922f;
      if (sm_s[n] && !allm) sc = FMIN_F;
      w_s[n] = sc;
    }
  }
  __syncthreads();
  float sc = w_s[tid];
  red_s[tid] = sc;
  __syncthreads();
  for (int s = 128; s > 0; s >>= 1) { if (tid < s) red_s[tid] = fmaxf(red_s[tid], red_s[tid + s]); __syncthreads(); }
  float mx = red_s[0];
  __syncthreads();
  float e = __expf(sc - mx);
  w_s[tid] = e;
  red_s[tid] = e;
  __syncthreads();
  for (int s = 128; s > 0; s >>= 1) { if (tid < s) red_s[tid] += red_s[tid + s]; __syncthreads(); }
  float invS = 1.f / red_s[0];
  __syncthreads();
  float o0 = 0.f, o1 = 0.f;
  const float* vbase = kv + (size_t)b * 193 * 1024 + 512;
#pragma unroll 4
  for (int n = 0; n < 193; ++n) {
    float w = w_s[n];
    const float* vr = vbase + (size_t)n * 1024;
    o0 += w * vr[tid];
    o1 += w * vr[tid + 256];
  }
  o0 = o0 * invS + pvb[tid];
  o1 = o1 * invS + pvb[tid + 256];
  red_s[tid] = o0 * o0 + o1 * o1;
  __syncthreads();
  for (int s = 128; s > 0; s >>= 1) { if (tid < s) red_s[tid] += red_s[tid + s]; __syncthreads(); }
  float scale = rsqrtf(red_s[0] * (1.f / 512.f) + 1e-6f);
  if (allm) scale = 0.f;
  out[((size_t)b * 16 + l) * 512 + tid] = o0 * scale * pnw[tid];
  out[((size_t)b * 16 + l) * 512 + tid + 256] = o1 * scale * pnw[tid + 256];
}

extern "C" void kernel_launch(void* const* d_in, const int* in_sizes, int n_in,
                              void* d_out, int out_size, void* d_ws, size_t ws_size,
                              hipStream_t stream) {
  (void)in_sizes; (void)n_in; (void)out_size; (void)ws_size;
  const float* tokens      = (const float*)d_in[0];
  const int*   lengths     = (const int*)d_in[1];
  const float* query       = (const float*)d_in[2];
  const float* comp_wv     = (const float*)d_in[3];
  const float* comp_bv     = (const float*)d_in[4];
  const float* comp_ww     = (const float*)d_in[5];
  const float* comp_bw     = (const float*)d_in[6];
  const float* comp_pos    = (const float*)d_in[7];
  const float* comp_norm_w = (const float*)d_in[8];
  const float* idx_qd_w    = (const float*)d_in[9];
  const float* idx_qd_b    = (const float*)d_in[10];
  const float* idx_qu_w    = (const float*)d_in[11];
  const float* idx_qu_b    = (const float*)d_in[12];
  const float* idx_k_w     = (const float*)d_in[13];
  const float* idx_k_b     = (const float*)d_in[14];
  const float* idx_hw_w    = (const float*)d_in[15];
  const float* idx_hw_b    = (const float*)d_in[16];
  const float* idx_qn_w    = (const float*)d_in[17];
  const float* idx_kn_w    = (const float*)d_in[18];
  const float* pool_latents= (const float*)d_in[19];
  const float* pool_q_w    = (const float*)d_in[20];
  const float* pool_q_b    = (const float*)d_in[21];
  const float* pool_k_w    = (const float*)d_in[22];
  const float* pool_k_b    = (const float*)d_in[23];
  const float* pool_v_w    = (const float*)d_in[24];
  const float* pool_v_b    = (const float*)d_in[25];
  const float* pool_norm_w = (const float*)d_in[26];

  char* ws = (char*)d_ws;
  unsigned short* A2    = (unsigned short*)(ws + 0);           // 128 MB [0, 134217728)
  float*          bt    = (float*)(ws + 0);                    // aliases (post-GEMM)
  float*          keys  = (float*)(ws + 4194304);
  int*            idxs  = (int*)  (ws + 4718592);
  int*            smask = (int*)  (ws + 4720640);
  float*          qproj = (float*)(ws + 4728832);
  unsigned short* src_bf= (unsigned short*)(ws + 5793792);
  float*          kv    = (float*)(ws + 7497728);
  float*          gpart = (float*)(ws + 134217728);            // 8 MB
  float*          ctx   = (float*)(ws + 142606336);            // 4 MB
  unsigned short* W2    = (unsigned short*)(ws + 146800640);   // 2 MB
  float*          gsum  = (float*)(ws + 148897792);            // 16 KB
  unsigned short* PW2   = (unsigned short*)(ws + 148914176);   // 1 MB — OUTSIDE A2 (survives GEMM)

  k_wpack4<<<dim3(8, 8, 4), 256, 0, stream>>>(comp_wv, comp_ww, pool_k_w,
                                              pool_v_w, W2, PW2);
  k_split<<<4096, 256, 0, stream>>>(tokens, lengths, A2, gpart);
  k_gemm128<<<dim3(8, 512), 256, 0, stream>>>(A2, W2, comp_bv, comp_bw,
                                              comp_pos, lengths, ctx);
  k_gq<<<32, 256, 0, stream>>>(gpart, gsum, query, pool_q_w, pool_q_b, qproj);
  k_btk<<<2048, 64, 0, stream>>>(ctx, comp_norm_w, idx_k_w, idx_k_b, idx_kn_w,
                                 bt, keys);
  k_sel<<<8, 256, 0, stream>>>(query, keys, lengths, idx_qd_w, idx_qd_b,
                               idx_qu_w, idx_qu_b, idx_hw_w, idx_hw_b,
                               idx_qn_w, idxs);
  k_src<<<dim3(8, 208), 128, 0, stream>>>(tokens, bt, gsum, lengths, idxs,
                                          src_bf, smask);
  k_kvm<<<dim3(13, 8), 256, 0, stream>>>(src_bf, PW2, kv);
  k_attn<<<dim3(8, 16), 256, 0, stream>>>(kv, qproj, pool_latents, pool_k_b,
                                          pool_v_b, pool_norm_w, smask,
                                          (float*)d_out);
}

// Round 16
// 383.218 us; speedup vs baseline: 1.1887x; 1.0501x over previous
//
#include <hip/hip_runtime.h>
#include <stdint.h>

typedef __attribute__((ext_vector_type(8))) _Float16 half8;
typedef __attribute__((ext_vector_type(8))) short short8;
typedef __attribute__((ext_vector_type(4))) float f32x4;

#define FMIN_F (-3.4028234663852886e38f)

__device__ __forceinline__ unsigned short rne_bf16(float x) {
  unsigned u = __float_as_uint(x);
  unsigned r = (u + 0x7FFFu + ((u >> 16) & 1u)) >> 16;
  return (unsigned short)r;
}

__device__ __forceinline__ void split16(float x, unsigned short& h, unsigned short& l) {
  _Float16 hh = (_Float16)x;
  float r = x - (float)hh;
  _Float16 ll = (_Float16)r;
  union { _Float16 f; unsigned short u; } a, b;
  a.f = hh; b.f = ll;
  h = a.u; l = b.u;
}

__device__ __forceinline__ void glds16(const unsigned short* g, unsigned short* l) {
  __builtin_amdgcn_global_load_lds(
      (const __attribute__((address_space(1))) unsigned int*)g,
      (__attribute__((address_space(3))) unsigned int*)l, 16, 0, 0);
}

// ---- fused prep: bid<4096 -> token split (+gpart partials); else weight pack --
__global__ __launch_bounds__(256) void k_prep(const float* __restrict__ tok,
    const int* __restrict__ lengths, unsigned short* __restrict__ A2,
    float* __restrict__ gpart, const float* __restrict__ wv,
    const float* __restrict__ ww, const float* __restrict__ pwk,
    const float* __restrict__ pwv, unsigned short* __restrict__ W2,
    unsigned short* __restrict__ PW) {
  __shared__ float sh[64 * 65];
  int bid = blockIdx.x, tid = threadIdx.x;
  if (bid < 4096) {
    // ---- token split: 16 rows per block + per-block partial column sums ----
    int colv = tid & 127;
    int rh = tid >> 7;
    int r0 = bid << 4;
    int b0 = r0 >> 13;
    int part = bid & 511;
    int len = lengths[b0];
    float sx = 0.f, sy = 0.f, sz = 0.f, sw = 0.f;
#pragma unroll
    for (int i = 0; i < 8; ++i) {
      int row = r0 + (i << 1) + rh;
      const float4 v = ((const float4*)(tok + (size_t)row * 512))[colv];
      ushort4 oh, ol;
      split16(v.x, oh.x, ol.x); split16(v.y, oh.y, ol.y);
      split16(v.z, oh.z, ol.z); split16(v.w, oh.w, ol.w);
      *(ushort4*)(A2 + (size_t)row * 1024 + colv * 4) = oh;
      *(ushort4*)(A2 + (size_t)row * 1024 + 512 + colv * 4) = ol;
      if ((row & 8191) < len) { sx += v.x; sy += v.y; sz += v.z; sw += v.w; }
    }
    if (rh == 0) {
      sh[colv * 4 + 0] = sx; sh[colv * 4 + 1] = sy;
      sh[colv * 4 + 2] = sz; sh[colv * 4 + 3] = sw;
    }
    __syncthreads();
    if (rh == 1) {
      sh[colv * 4 + 0] += sx; sh[colv * 4 + 1] += sy;
      sh[colv * 4 + 2] += sz; sh[colv * 4 + 3] += sw;
    }
    __syncthreads();
    float* gp = gpart + ((size_t)b0 * 512 + part) * 512;
    gp[tid] = sh[tid];
    gp[tid + 256] = sh[tid + 256];
  } else {
    // ---- weight pack: z<2 -> comp W2 split-f16 ; z>=2 -> pool PW bf16 ----
    int idx = bid - 4096;
    int z = idx >> 6;
    int rem = idx & 63;
    int kk0 = (rem >> 3) * 64, d0 = (rem & 7) * 64;
    const float* W = (z == 0) ? wv : (z == 1) ? ww : (z == 2) ? pwk : pwv;
    for (int i = tid; i < 4096; i += 256) {
      int k = i >> 6, d = i & 63;
      sh[k * 65 + d] = W[(size_t)(kk0 + k) * 512 + d0 + d];
    }
    __syncthreads();
    int dr = tid >> 2, kq = tid & 3;
    if (z < 2) {
      int m = z;
      int d = d0 + dr;
      int n = (d >> 5) * 64 + m * 32 + (d & 31);
      size_t baseH = (size_t)n * 1024 + kk0 + kq * 16;
      for (int q = 0; q < 16; ++q) {
        unsigned short hh, ll;
        split16(sh[(kq * 16 + q) * 65 + dr], hh, ll);
        W2[baseH + q] = hh;
        W2[baseH + 512 + q] = ll;
      }
    } else {
      int m = z - 2;
      int n = m * 512 + d0 + dr;
      size_t base = (size_t)n * 512 + kk0 + kq * 16;
      for (int q = 0; q < 16; ++q)
        PW[base + q] = rne_bf16(sh[(kq * 16 + q) * 65 + dr]);
    }
  }
}

// ---- 128x128-tile split-f16 GEMM + XOR-swizzled LDS + XCD-local A-panels ------
__global__ __launch_bounds__(256) void k_gemm128(
    const unsigned short* __restrict__ A2, const unsigned short* __restrict__ W2,
    const float* __restrict__ bv, const float* __restrict__ bw,
    const float* __restrict__ cpos, const int* __restrict__ lengths,
    float* __restrict__ ctx) {
  __shared__ __align__(16) unsigned short Ash[128 * 64];
  __shared__ __align__(16) unsigned short Asl[128 * 64];
  __shared__ __align__(16) unsigned short Bsh[128 * 64];
  __shared__ __align__(16) unsigned short Bsl[128 * 64];
  __shared__ float pos_s[32 * 64];
  int ny = blockIdx.y & 7;
  int mt = blockIdx.x * 64 + (blockIdx.y >> 3);
  int tid = threadIdx.x;
  int wave = tid >> 6, lane = tid & 63;
  int m0 = mt << 7, n0 = ny << 7;
  for (int i = tid; i < 2048; i += 256) {
    int s = i >> 6, c = i & 63;
    pos_s[i] = cpos[s * 512 + ny * 64 + c];
  }
  f32x4 acc[4][4];
#pragma unroll
  for (int i = 0; i < 4; ++i)
#pragma unroll
    for (int j = 0; j < 4; ++j) acc[i][j] = (f32x4){0.f, 0.f, 0.f, 0.f};
  int lrow = lane >> 3, lcol = lane & 7;
  int wm = wave >> 1, wn = wave & 1;
  int l15 = lane & 15, lg4 = lane >> 4;
  int scs_ = (lcol ^ lrow) * 8;
  int rx = (l15 & 7);
  for (int kk = 0; kk < 8; ++kk) {
    int k0 = kk << 6;
#pragma unroll
    for (int j = 0; j < 4; ++j) {
      int r = wave * 32 + j * 8 + lrow;
      size_t ga = (size_t)(m0 + r) * 1024 + k0 + scs_;
      size_t gb = (size_t)(n0 + r) * 1024 + k0 + scs_;
      int ls = r * 64 + lcol * 8;
      glds16(A2 + ga, Ash + ls);
      glds16(A2 + ga + 512, Asl + ls);
      glds16(W2 + gb, Bsh + ls);
      glds16(W2 + gb + 512, Bsl + ls);
    }
    __syncthreads();
#pragma unroll
    for (int ks = 0; ks < 2; ++ks) {
      int cofs = ((ks * 4 + lg4) ^ rx) * 8;
      half8 bh[4], bl[4];
#pragma unroll
      for (int i = 0; i < 4; ++i) {
        bh[i] = *(const half8*)(Bsh + (wn * 64 + i * 16 + l15) * 64 + cofs);
        bl[i] = *(const half8*)(Bsl + (wn * 64 + i * 16 + l15) * 64 + cofs);
      }
#pragma unroll
      for (int mi = 0; mi < 4; ++mi) {
        half8 ah = *(const half8*)(Ash + (wm * 64 + mi * 16 + l15) * 64 + cofs);
        half8 al = *(const half8*)(Asl + (wm * 64 + mi * 16 + l15) * 64 + cofs);
#pragma unroll
        for (int ni = 0; ni < 4; ++ni) {
          acc[mi][ni] = __builtin_amdgcn_mfma_f32_16x16x32_f16(ah, bh[ni], acc[mi][ni], 0, 0, 0);
          acc[mi][ni] = __builtin_amdgcn_mfma_f32_16x16x32_f16(al, bh[ni], acc[mi][ni], 0, 0, 0);
          acc[mi][ni] = __builtin_amdgcn_mfma_f32_16x16x32_f16(ah, bl[ni], acc[mi][ni], 0, 0, 0);
        }
      }
    }
    __syncthreads();
  }
  int bidx = m0 >> 13;
  int len = lengths[bidx];
#pragma unroll
  for (int niv = 0; niv < 2; ++niv) {
    int d = (ny * 2 + wn) * 32 + niv * 16 + l15;
    int dloc = wn * 32 + niv * 16 + l15;
    float bwv = bw[d], bvv = bv[d];
#pragma unroll
    for (int blk = 0; blk < 2; ++blk) {
      int growL = m0 + wm * 64 + blk * 32;
      int nb = (growL & 8191) >> 5;
      int vcnt = min(max(len - nb * 32, 0), 32);
      float lg[8], vl[8];
      float mx = FMIN_F;
#pragma unroll
      for (int j = 0; j < 8; ++j) {
        int mi = blk * 2 + (j >> 2);
        int r = j & 3;
        int s = ((j >> 2) << 4) + lg4 * 4 + r;
        float L = acc[mi][2 + niv][r] + bwv + pos_s[s * 64 + dloc];
        float V = acc[mi][niv][r] + bvv;
        lg[j] = L; vl[j] = V;
        if (s < vcnt) mx = fmaxf(mx, L);
      }
      mx = fmaxf(mx, __shfl_xor(mx, 16));
      mx = fmaxf(mx, __shfl_xor(mx, 32));
      float num = 0.f, den = 0.f;
#pragma unroll
      for (int j = 0; j < 8; ++j) {
        int s = ((j >> 2) << 4) + lg4 * 4 + (j & 3);
        if (s < vcnt) {
          float e = __expf(lg[j] - mx);
          num += e * vl[j];
          den += e;
        }
      }
      num += __shfl_xor(num, 16); num += __shfl_xor(num, 32);
      den += __shfl_xor(den, 16); den += __shfl_xor(den, 32);
      float o = (den > 0.f) ? (num / den) : 0.f;
      if (lg4 == 0)
        ctx[((size_t)bidx * 256 + nb) * 512 + d] = o;
    }
  }
}

// ---- fused 64-thread post-GEMM: btk (2048) | gred (64) | qproj (64) -----------
__global__ __launch_bounds__(64) void k_btkq(const float* __restrict__ ctx,
    const float* __restrict__ nw, const float* __restrict__ kw,
    const float* __restrict__ kb, const float* __restrict__ knw,
    float* __restrict__ bt, float* __restrict__ keys,
    const float* __restrict__ gpart, float* __restrict__ gsum,
    const float* __restrict__ query, const float* __restrict__ pqw,
    const float* __restrict__ pqb, float* __restrict__ qp) {
  __shared__ float bs[512];
  int bid = blockIdx.x, lane = threadIdx.x;
  if (bid < 2048) {
    int row = bid;
    const float* cp = ctx + (size_t)row * 512 + lane * 8;
    float x[8];
#pragma unroll
    for (int j = 0; j < 8; ++j) x[j] = cp[j];
    float ss = 0.f;
#pragma unroll
    for (int j = 0; j < 8; ++j) ss += x[j] * x[j];
#pragma unroll
    for (int o = 1; o < 64; o <<= 1) ss += __shfl_xor(ss, o);
    float sc = rsqrtf(ss * (1.f / 512.f) + 1e-6f);
    float* op = bt + (size_t)row * 512 + lane * 8;
    const float* nwp = nw + lane * 8;
#pragma unroll
    for (int j = 0; j < 8; ++j) {
      float y = x[j] * sc * nwp[j];
      op[j] = y;
      bs[lane * 8 + j] = y;
    }
    __syncthreads();
    float a = kb[lane];
    for (int k = 0; k < 512; ++k) a += bs[k] * kw[k * 64 + lane];
    float s2 = a * a;
#pragma unroll
    for (int o = 1; o < 64; o <<= 1) s2 += __shfl_xor(s2, o);
    keys[(size_t)row * 64 + lane] = a * rsqrtf(s2 * (1.f / 64.f) + 1e-6f) * knw[lane];
  } else if (bid < 2112) {
    int t = bid - 2048;
    int b = t >> 3, c = (t & 7) * 64 + lane;
    float a0 = 0.f;
    for (int part = 0; part < 512; ++part)
      a0 += gpart[((size_t)b * 512 + part) * 512 + c];
    gsum[b * 512 + c] = a0;
  } else {
    int t = bid - 2112;
    int b = t >> 3, c = (t & 7) * 64 + lane;
    for (int i = lane; i < 512; i += 64) bs[i] = query[b * 512 + i];
    __syncthreads();
    float a = pqb[c];
    for (int k = 0; k < 512; ++k) a += bs[k] * pqw[(size_t)k * 512 + c];
    qp[b * 512 + c] = a;
  }
}

// ---- per-b: ql, qh, hw, scores, top-64 ----------------------------------------
__global__ __launch_bounds__(256) void k_sel(
    const float* __restrict__ query, const float* __restrict__ keys,
    const int* __restrict__ lengths,
    const float* __restrict__ qdw, const float* __restrict__ qdb,
    const float* __restrict__ quw, const float* __restrict__ qub,
    const float* __restrict__ hww, const float* __restrict__ hwb,
    const float* __restrict__ qnw, int* __restrict__ idxs) {
  int b = blockIdx.x, tid = threadIdx.x;
  __shared__ float qs[512], qls[64], qhs[512], hws[8], scs[256];
  __shared__ float ks_s[256 * 65];
  int wave = tid >> 6, lane = tid & 63;
  {
    const float* kb_g = keys + (size_t)b * 256 * 64;
    for (int r = wave; r < 256; r += 4)
      ks_s[r * 65 + lane] = kb_g[r * 64 + lane];
  }
  for (int i = tid; i < 512; i += 256) qs[i] = query[b * 512 + i];
  __syncthreads();
  if (tid < 64) {
    float a = qdb[tid];
    for (int k = 0; k < 512; ++k) a += qs[k] * qdw[k * 64 + tid];
    float ss = a * a;
#pragma unroll
    for (int o = 1; o < 64; o <<= 1) ss += __shfl_xor(ss, o);
    qls[tid] = a * rsqrtf(ss * (1.f / 64.f) + 1e-6f) * qnw[tid];
  }
  __syncthreads();
  for (int j = tid; j < 512; j += 256) {
    float a = qub[j];
    for (int k = 0; k < 64; ++k) a += qls[k] * quw[k * 512 + j];
    qhs[j] = a;
  }
  if (tid < 8) {
    float a = hwb[tid];
    for (int k = 0; k < 512; ++k) a += qs[k] * hww[k * 8 + tid];
    hws[tid] = a;
  }
  __syncthreads();
  if (tid == 0) {
    float m = hws[0];
    for (int h = 1; h < 8; ++h) m = fmaxf(m, hws[h]);
    float s = 0.f, e[8];
    for (int h = 0; h < 8; ++h) { e[h] = __expf(hws[h] - m); s += e[h]; }
    for (int h = 0; h < 8; ++h) hws[h] = e[h] / s;
  }
  __syncthreads();
  {
    int len = lengths[b];
    int n = tid;
    float sc = FMIN_F;
    if (n * 32 < len) {
      sc = 0.f;
      const float* kr = ks_s + n * 65;
      for (int h = 0; h < 8; ++h) {
        float dp = 0.f;
#pragma unroll
        for (int i = 0; i < 64; ++i) dp += qhs[h * 64 + i] * kr[i];
        sc += fmaxf(dp, 0.f) * hws[h];
      }
    }
    scs[n] = sc;
  }
  __syncthreads();
  if (tid < 64) {
    unsigned long long kk[4];
#pragma unroll
    for (int j = 0; j < 4; ++j) {
      int n = j * 64 + tid;
      unsigned u = __float_as_uint(scs[n]);
      u = (u & 0x80000000u) ? ~u : (u | 0x80000000u);
      kk[j] = ((unsigned long long)u << 32) | (unsigned long long)(255 - n);
    }
    for (int r = 0; r < 64; ++r) {
      unsigned long long m = kk[0];
      if (kk[1] > m) m = kk[1];
      if (kk[2] > m) m = kk[2];
      if (kk[3] > m) m = kk[3];
#pragma unroll
      for (int o = 1; o < 64; o <<= 1) {
        unsigned long long t = __shfl_xor(m, o);
        if (t > m) m = t;
      }
      if (tid == 0) idxs[b * 64 + r] = 255 - (int)(m & 0xFFull);
#pragma unroll
      for (int j = 0; j < 4; ++j) if (kk[j] == m) kk[j] = 0ull;
    }
  }
}

// ---- assemble src rows (recent | sel | gtok) as bf16 + smask + zero pad rows --
__global__ __launch_bounds__(128) void k_src(const float* __restrict__ tok,
    const float* __restrict__ bt, const float* __restrict__ gsum,
    const int* __restrict__ lengths, const int* __restrict__ idxs,
    unsigned short* __restrict__ src_bf, int* __restrict__ smask) {
  int b = blockIdx.x, n = blockIdx.y, tid = threadIdx.x;
  int d0 = tid * 4;
  if (n >= 193) {
    size_t prow = 1544 + (size_t)b * 15 + (n - 193);
    ushort4 z; z.x = 0; z.y = 0; z.z = 0; z.w = 0;
    *(ushort4*)(src_bf + prow * 512 + d0) = z;
    return;
  }
  int len = lengths[b];
  float v0 = 0.f, v1 = 0.f, v2 = 0.f, v3 = 0.f;
  int sm = 0;
  if (n < 128) {
    int cl = min(max(len, 0), 8192);
    int start = max(cl - 128, 0);
    int pos = min(start + n, 8191);
    bool vis = n < min(cl, 128);
    sm = vis ? 0 : 1;
    if (vis) {
      const float* tp = tok + ((size_t)b * 8192 + pos) * 512 + d0;
      float pn = (float)n;
#pragma unroll
      for (int j = 0; j < 4; ++j) {
        int d = d0 + j;
        int i = d >> 1;
        float ang = pn * __expf(-9.210340371976184f * ((float)i * (1.f / 256.f)));
        float pe = (d & 1) ? cosf(ang) : sinf(ang);
        float t = tp[j] + pe;
        if (j == 0) v0 = t; else if (j == 1) v1 = t; else if (j == 2) v2 = t; else v3 = t;
      }
    }
  } else if (n < 192) {
    int idx = idxs[b * 64 + (n - 128)];
    sm = (idx * 32 >= len) ? 1 : 0;
    const float* bp = bt + ((size_t)b * 256 + idx) * 512 + d0;
    v0 = bp[0]; v1 = bp[1]; v2 = bp[2]; v3 = bp[3];
  } else {
    sm = 0;
    float inv = 1.f / (float)max(len, 1);
    const float* gp = gsum + b * 512 + d0;
    v0 = gp[0] * inv; v1 = gp[1] * inv; v2 = gp[2] * inv; v3 = gp[3] * inv;
  }
  ushort4 o;
  o.x = rne_bf16(v0); o.y = rne_bf16(v1); o.z = rne_bf16(v2); o.w = rne_bf16(v3);
  *(ushort4*)(src_bf + ((size_t)b * 193 + n) * 512 + d0) = o;
  if (tid == 0) smask[b * 193 + n] = sm;
}

// ---- pooling k/v GEMM (bf16 MFMA) ---------------------------------------------
__global__ __launch_bounds__(256) void k_kvm(
    const unsigned short* __restrict__ src_bf, const unsigned short* __restrict__ PW,
    float* __restrict__ kv) {
  __shared__ __align__(16) unsigned short As[128 * 64];
  __shared__ __align__(16) unsigned short Bs[128 * 64];
  int m0 = blockIdx.x << 7, n0 = blockIdx.y << 7;
  int tid = threadIdx.x;
  int wave = tid >> 6, lane = tid & 63;
  int wm = wave >> 1, wn = wave & 1;
  int l15 = lane & 15, lg4 = lane >> 4;
  int lrow = lane >> 3, lcol = lane & 7;
  f32x4 acc[4][4];
#pragma unroll
  for (int i = 0; i < 4; ++i)
#pragma unroll
    for (int j = 0; j < 4; ++j) acc[i][j] = (f32x4){0.f, 0.f, 0.f, 0.f};
  for (int kk = 0; kk < 8; ++kk) {
    int k0 = kk << 6;
#pragma unroll
    for (int j = 0; j < 4; ++j) {
      int r = wave * 32 + j * 8 + lrow;
      glds16(src_bf + (size_t)(m0 + r) * 512 + k0 + lcol * 8, As + r * 64 + lcol * 8);
      glds16(PW + (size_t)(n0 + r) * 512 + k0 + lcol * 8, Bs + r * 64 + lcol * 8);
    }
    __syncthreads();
#pragma unroll
    for (int ks = 0; ks < 2; ++ks) {
      int kb = ks * 32 + lg4 * 8;
      short8 av[4], bf[4];
#pragma unroll
      for (int i = 0; i < 4; ++i) {
        av[i] = *(const short8*)(As + (wm * 64 + i * 16 + l15) * 64 + kb);
        bf[i] = *(const short8*)(Bs + (wn * 64 + i * 16 + l15) * 64 + kb);
      }
#pragma unroll
      for (int mi = 0; mi < 4; ++mi)
#pragma unroll
        for (int ni = 0; ni < 4; ++ni)
          acc[mi][ni] = __builtin_amdgcn_mfma_f32_16x16x32_bf16(av[mi], bf[ni], acc[mi][ni], 0, 0, 0);
    }
    __syncthreads();
  }
#pragma unroll
  for (int mi = 0; mi < 4; ++mi)
#pragma unroll
    for (int ni = 0; ni < 4; ++ni)
#pragma unroll
      for (int rr = 0; rr < 4; ++rr) {
        int grow = m0 + wm * 64 + mi * 16 + lg4 * 4 + rr;
        kv[(size_t)grow * 1024 + n0 + wn * 64 + ni * 16 + l15] = acc[mi][ni][rr];
      }
}

// ---- latent cross-attention + rmsnorm -> out ----------------------------------
__global__ __launch_bounds__(256) void k_attn(const float* __restrict__ kv,
    const float* __restrict__ qproj, const float* __restrict__ latents,
    const float* __restrict__ pkb, const float* __restrict__ pvb,
    const float* __restrict__ pnw, const int* __restrict__ smask,
    float* __restrict__ out) {
  int b = blockIdx.x, l = blockIdx.y, tid = threadIdx.x;
  int wave = tid >> 6, lane = tid & 63;
  __shared__ float lq_s[512];
  __shared__ float w_s[256];
  __shared__ float red_s[256];
  __shared__ int sm_s[256];
  for (int i = tid; i < 512; i += 256) lq_s[i] = latents[l * 512 + i] + qproj[b * 512 + i];
  sm_s[tid] = (tid < 193) ? smask[b * 193 + tid] : 1;
  w_s[tid] = FMIN_F;
  __syncthreads();
  red_s[tid] = (tid < 193 && sm_s[tid]) ? 1.f : 0.f;
  __syncthreads();
  for (int s = 128; s > 0; s >>= 1) { if (tid < s) red_s[tid] += red_s[tid + s]; __syncthreads(); }
  bool allm = (red_s[0] > 192.5f);
  __syncthreads();
  red_s[tid] = pkb[tid] * lq_s[tid] + pkb[tid + 256] * lq_s[tid + 256];
  __syncthreads();
  for (int s = 128; s > 0; s >>= 1) { if (tid < s) red_s[tid] += red_s[tid + s]; __syncthreads(); }
  float pkbdot = red_s[0];
  __syncthreads();
  for (int n = wave; n < 193; n += 4) {
    const float* kr = kv + ((size_t)b * 193 + n) * 1024 + lane * 8;
    float4 a = *(const float4*)(kr);
    float4 c = *(const float4*)(kr + 4);
    const float* lq = lq_s + lane * 8;
    float dp = a.x * lq[0] + a.y * lq[1] + a.z * lq[2] + a.w * lq[3]
             + c.x * lq[4] + c.y * lq[5] + c.z * lq[6] + c.w * lq[7];
#pragma unroll
    for (int o = 1; o < 64; o <<= 1) dp += __shfl_xor(dp, o);
    if (lane == 0) {
      float sc = (dp + pkbdot) * 0.04419417382415922f;
      if (sm_s[n] && !allm) sc = FMIN_F;
      w_s[n] = sc;
    }
  }
  __syncthreads();
  float sc = w_s[tid];
  red_s[tid] = sc;
  __syncthreads();
  for (int s = 128; s > 0; s >>= 1) { if (tid < s) red_s[tid] = fmaxf(red_s[tid], red_s[tid + s]); __syncthreads(); }
  float mx = red_s[0];
  __syncthreads();
  float e = __expf(sc - mx);
  w_s[tid] = e;
  red_s[tid] = e;
  __syncthreads();
  for (int s = 128; s > 0; s >>= 1) { if (tid < s) red_s[tid] += red_s[tid + s]; __syncthreads(); }
  float invS = 1.f / red_s[0];
  __syncthreads();
  float o0 = 0.f, o1 = 0.f;
  const float* vbase = kv + (size_t)b * 193 * 1024 + 512;
#pragma unroll 4
  for (int n = 0; n < 193; ++n) {
    float w = w_s[n];
    const float* vr = vbase + (size_t)n * 1024;
    o0 += w * vr[tid];
    o1 += w * vr[tid + 256];
  }
  o0 = o0 * invS + pvb[tid];
  o1 = o1 * invS + pvb[tid + 256];
  red_s[tid] = o0 * o0 + o1 * o1;
  __syncthreads();
  for (int s = 128; s > 0; s >>= 1) { if (tid < s) red_s[tid] += red_s[tid + s]; __syncthreads(); }
  float scale = rsqrtf(red_s[0] * (1.f / 512.f) + 1e-6f);
  if (allm) scale = 0.f;
  out[((size_t)b * 16 + l) * 512 + tid] = o0 * scale * pnw[tid];
  out[((size_t)b * 16 + l) * 512 + tid + 256] = o1 * scale * pnw[tid + 256];
}

extern "C" void kernel_launch(void* const* d_in, const int* in_sizes, int n_in,
                              void* d_out, int out_size, void* d_ws, size_t ws_size,
                              hipStream_t stream) {
  (void)in_sizes; (void)n_in; (void)out_size; (void)ws_size;
  const float* tokens      = (const float*)d_in[0];
  const int*   lengths     = (const int*)d_in[1];
  const float* query       = (const float*)d_in[2];
  const float* comp_wv     = (const float*)d_in[3];
  const float* comp_bv     = (const float*)d_in[4];
  const float* comp_ww     = (const float*)d_in[5];
  const float* comp_bw     = (const float*)d_in[6];
  const float* comp_pos    = (const float*)d_in[7];
  const float* comp_norm_w = (const float*)d_in[8];
  const float* idx_qd_w    = (const float*)d_in[9];
  const float* idx_qd_b    = (const float*)d_in[10];
  const float* idx_qu_w    = (const float*)d_in[11];
  const float* idx_qu_b    = (const float*)d_in[12];
  const float* idx_k_w     = (const float*)d_in[13];
  const float* idx_k_b     = (const float*)d_in[14];
  const float* idx_hw_w    = (const float*)d_in[15];
  const float* idx_hw_b    = (const float*)d_in[16];
  const float* idx_qn_w    = (const float*)d_in[17];
  const float* idx_kn_w    = (const float*)d_in[18];
  const float* pool_latents= (const float*)d_in[19];
  const float* pool_q_w    = (const float*)d_in[20];
  const float* pool_q_b    = (const float*)d_in[21];
  const float* pool_k_w    = (const float*)d_in[22];
  const float* pool_k_b    = (const float*)d_in[23];
  const float* pool_v_w    = (const float*)d_in[24];
  const float* pool_v_b    = (const float*)d_in[25];
  const float* pool_norm_w = (const float*)d_in[26];

  char* ws = (char*)d_ws;
  unsigned short* A2    = (unsigned short*)(ws + 0);           // 128 MB [0, 134217728)
  float*          bt    = (float*)(ws + 0);                    // aliases (post-GEMM)
  float*          keys  = (float*)(ws + 4194304);
  int*            idxs  = (int*)  (ws + 4718592);
  int*            smask = (int*)  (ws + 4720640);
  float*          qproj = (float*)(ws + 4728832);
  unsigned short* src_bf= (unsigned short*)(ws + 5793792);
  float*          kv    = (float*)(ws + 7497728);
  float*          gpart = (float*)(ws + 134217728);            // 8 MB
  float*          ctx   = (float*)(ws + 142606336);            // 4 MB
  unsigned short* W2    = (unsigned short*)(ws + 146800640);   // 2 MB
  float*          gsum  = (float*)(ws + 148897792);            // 16 KB
  unsigned short* PW2   = (unsigned short*)(ws + 148914176);   // 1 MB — outside A2

  k_prep<<<4352, 256, 0, stream>>>(tokens, lengths, A2, gpart, comp_wv, comp_ww,
                                   pool_k_w, pool_v_w, W2, PW2);
  k_gemm128<<<dim3(8, 512), 256, 0, stream>>>(A2, W2, comp_bv, comp_bw,
                                              comp_pos, lengths, ctx);
  k_btkq<<<2176, 64, 0, stream>>>(ctx, comp_norm_w, idx_k_w, idx_k_b, idx_kn_w,
                                  bt, keys, gpart, gsum, query, pool_q_w,
                                  pool_q_b, qproj);
  k_sel<<<8, 256, 0, stream>>>(query, keys, lengths, idx_qd_w, idx_qd_b,
                               idx_qu_w, idx_qu_b, idx_hw_w, idx_hw_b,
                               idx_qn_w, idxs);
  k_src<<<dim3(8, 208), 128, 0, stream>>>(tokens, bt, gsum, lengths, idxs,
                                          src_bf, smask);
  k_kvm<<<dim3(13, 8), 256, 0, stream>>>(src_bf, PW2, kv);
  k_attn<<<dim3(8, 16), 256, 0, stream>>>(kv, qproj, pool_latents, pool_k_b,
                                          pool_v_b, pool_norm_w, smask,
                                          (float*)d_out);
}